// Round 16
// baseline (3244.611 us; speedup 1.0000x reference)
//
#include <hip/hip_runtime.h>
#include <hip/hip_bf16.h>
#include <math.h>

typedef unsigned int   u32;
typedef unsigned short u16;
typedef __bf16 bf16x8 __attribute__((ext_vector_type(8)));
typedef float  f32x4  __attribute__((ext_vector_type(4)));
typedef u16    u16x8  __attribute__((ext_vector_type(8)));
typedef u16    u16x4  __attribute__((ext_vector_type(4)));

constexpr int BB = 32, DD = 768, LL = 197, HH = 12, NTOK = 196;
constexpr int MROWS = BB * LL;        // 6304
constexpr int MTOK  = BB * NTOK;      // 6272

__device__ __forceinline__ u16 f2bf(float f) {
    union { float f; u32 u; } v; v.f = f;
    u32 r = v.u + 0x7fff + ((v.u >> 16) & 1);
    return (u16)(r >> 16);
}
__device__ __forceinline__ float bf2f(u16 u) {
    union { u32 u; float f; } v; v.u = ((u32)u) << 16;
    return v.f;
}

#define AS1 __attribute__((address_space(1)))
#define AS3 __attribute__((address_space(3)))
__device__ __forceinline__ void gload_lds16(const void* g, void* l) {
    __builtin_amdgcn_global_load_lds((const AS1 u32*)g, (AS3 u32*)l, 16, 0, 0);
}

// ---------------------------------------------------------------------------
__global__ void cast_kernel(const float* __restrict__ in, u16* __restrict__ out, int n)
{
    int i4 = (blockIdx.x * 256 + threadIdx.x) * 4;
    if (i4 >= n) return;
    float4 v = *reinterpret_cast<const float4*>(in + i4);
    out[i4]   = f2bf(v.x); out[i4+1] = f2bf(v.y);
    out[i4+2] = f2bf(v.z); out[i4+3] = f2bf(v.w);
}

__global__ void cast4_kernel(const float* s0, int n0, const float* s1, int n1,
                             const float* s2, int n2, const float* s3, int n3,
                             u16* d0, u16* d1, u16* d2, u16* d3)
{
    int i4 = (blockIdx.x * 256 + threadIdx.x) * 4;
    const float* s; u16* d; int off;
    if      (i4 < n0)            { s = s0; d = d0; off = i4; }
    else if (i4 < n0+n1)         { s = s1; d = d1; off = i4 - n0; }
    else if (i4 < n0+n1+n2)      { s = s2; d = d2; off = i4 - n0 - n1; }
    else if (i4 < n0+n1+n2+n3)   { s = s3; d = d3; off = i4 - n0 - n1 - n2; }
    else return;
    float4 v = *reinterpret_cast<const float4*>(s + off);
    d[off]   = f2bf(v.x); d[off+1] = f2bf(v.y);
    d[off+2] = f2bf(v.z); d[off+3] = f2bf(v.w);
}

// ---------------------------------------------------------------------------
__global__ void patchify_kernel(const float* __restrict__ src, int C,
                                u16* __restrict__ out, int total)
{
    int idx = blockIdx.x * 256 + threadIdx.x;
    if (idx >= total) return;
    int K = C * 256;
    int row = idx / K, k = idx % K;
    int b = row / NTOK, n = row % NTOK;
    int c = k >> 8, rem = k & 255, pi = rem >> 4, pj = rem & 15;
    int i14 = n / 14, j14 = n % 14;
    float v = src[(((size_t)b * C + c) * 224 + i14 * 16 + pi) * 224 + j14 * 16 + pj];
    out[idx] = f2bf(v);
}

// ---------------------------------------------------------------------------
// bf16 MFMA GEMM — 256x128 tile, 8 waves, BK=32, single-barrier dbuf,
// XOR-swizzled conflict-free staging (all r15-verified).
// MODE 0: f32 +bias   MODE 1: GELU->bf16 +bias   MODE 2: f32 +bias+res
// MODE 3: batched bias-GEMM   MODE 4: bf16 +bias
// MODE 5: split-K=2, raw f32 partial store to Cout + z*M*N (no bias)
// ---------------------------------------------------------------------------
template<int MODE>
__global__ __launch_bounds__(512) void gemm_bf16(
    const u16* __restrict__ A, const u16* __restrict__ W,
    const float* __restrict__ bias, const float* __restrict__ res,
    void* __restrict__ Cout, int M, int N, int K, long long strideA)
{
    __shared__ u16 As[2][8192];   // 256 rows x 32 k
    __shared__ u16 Bs[2][4096];   // 128 rows x 32 k
    const int tid  = threadIdx.x;
    const int wave = tid >> 6, lane = tid & 63;
    const int lo = lane & 15, hi = lane >> 4;
    const int wr = wave >> 1, wc = wave & 1;

    const int m0 = blockIdx.y * 256, n0 = blockIdx.x * 128;
    if (MODE == 3) { A += blockIdx.z * strideA; W += blockIdx.z * strideA; }

    const int Klen = (MODE == 5) ? (K >> 1) : K;
    const int kb   = (MODE == 5) ? blockIdx.z * Klen : 0;

    const int limA = M - 1;
    const int limB = (MODE == 3 ? M : N) - 1;
    const int srow = lane >> 2;
    const int scol = ((lane & 3) ^ ((lane >> 3) & 3)) << 3;
    int ra0 = m0 + wave * 16 + srow;        if (ra0 > limA) ra0 = limA;
    int ra1 = m0 + 128 + wave * 16 + srow;  if (ra1 > limA) ra1 = limA;
    int rb0 = n0 + wave * 16 + srow;        if (rb0 > limB) rb0 = limB;
    const u16* Arow0 = A + (size_t)ra0 * K + kb + scol;
    const u16* Arow1 = A + (size_t)ra1 * K + kb + scol;
    const u16* Brow0 = W + (size_t)rb0 * K + kb + scol;

    const int fro = lo * 32 + ((hi ^ ((lo >> 1) & 3)) << 3);

    f32x4 acc[4][4] = {};

    #define STAGE(bf_, k0_)                                         \
        do {                                                        \
            gload_lds16(Arow0 + (k0_), &As[bf_][wave * 512]);       \
            gload_lds16(Arow1 + (k0_), &As[bf_][4096 + wave * 512]);\
            gload_lds16(Brow0 + (k0_), &Bs[bf_][wave * 512]);       \
        } while (0)

    #define COMPUTE(bf_)                                                         \
        do {                                                                     \
            bf16x8 af[4], bfr[4];                                                \
            _Pragma("unroll")                                                    \
            for (int i = 0; i < 4; ++i)                                          \
                af[i] = *reinterpret_cast<const bf16x8*>(                        \
                    &As[bf_][(wr * 4 + i) * 512 + fro]);                         \
            _Pragma("unroll")                                                    \
            for (int j = 0; j < 4; ++j)                                          \
                bfr[j] = *reinterpret_cast<const bf16x8*>(                       \
                    &Bs[bf_][(wc * 4 + j) * 512 + fro]);                         \
            _Pragma("unroll")                                                    \
            for (int i = 0; i < 4; ++i)                                          \
                _Pragma("unroll")                                                \
                for (int j = 0; j < 4; ++j)                                      \
                    acc[i][j] = __builtin_amdgcn_mfma_f32_16x16x32_bf16(         \
                        af[i], bfr[j], acc[i][j], 0, 0, 0);                      \
        } while (0)

    const int nt = Klen >> 5;   // even at all call sites (8,12,24,48,96)
    STAGE(0, 0);
    __syncthreads();
    int t = 0;
    for (; t + 2 < nt; t += 2) {
        STAGE(1, (t + 1) * 32);
        COMPUTE(0);
        __syncthreads();
        STAGE(0, (t + 2) * 32);
        COMPUTE(1);
        __syncthreads();
    }
    STAGE(1, (t + 1) * 32);
    COMPUTE(0);
    __syncthreads();
    COMPUTE(1);
    #undef STAGE
    #undef COMPUTE

    const size_t zoff = (MODE == 5) ? (size_t)blockIdx.z * M * N : 0;
    const int cr = hi * 4;
    const int cc = lo;
    #pragma unroll
    for (int i = 0; i < 4; ++i) {
        #pragma unroll
        for (int r = 0; r < 4; ++r) {
            int m = m0 + wr * 64 + i * 16 + cr + r;
            if (MODE != 3 && m >= M) continue;
            #pragma unroll
            for (int j = 0; j < 4; ++j) {
                int n = n0 + wc * 64 + j * 16 + cc;
                float v = acc[i][j][r];
                if (MODE == 0) {
                    ((float*)Cout)[(size_t)m * N + n] = v + bias[n];
                } else if (MODE == 1) {
                    float t2 = v + bias[n];
                    t2 = 0.5f * t2 * (1.f + erff(t2 * 0.70710678118654752f));
                    ((u16*)Cout)[(size_t)m * N + n] = f2bf(t2);
                } else if (MODE == 2) {
                    ((float*)Cout)[(size_t)m * N + n] = v + bias[n] + res[(size_t)m * N + n];
                } else if (MODE == 4) {
                    ((u16*)Cout)[(size_t)m * N + n] = f2bf(v + bias[n]);
                } else if (MODE == 5) {
                    ((float*)Cout)[zoff + (size_t)m * N + n] = v;
                } else { // MODE 3
                    if (m < M && n < M) {
                        float* C3 = (float*)Cout + (size_t)blockIdx.z * LL * LL;
                        C3[(size_t)(m + 1) * LL + (n + 1)] = v * 0.03608439182435161f;
                    }
                }
            }
        }
    }
}

// x[i] += p0[i] + p1[i] + bias[i % N]   (split-K reduce, N % 4 == 0)
__global__ void splitk_reduce_kernel(float* __restrict__ x, const float* __restrict__ p,
                                     const float* __restrict__ bias, int MN, int N)
{
    int i4 = (blockIdx.x * 256 + threadIdx.x) * 4;
    if (i4 >= MN) return;
    float4 a  = *reinterpret_cast<const float4*>(x + i4);
    float4 p0 = *reinterpret_cast<const float4*>(p + i4);
    float4 p1 = *reinterpret_cast<const float4*>(p + (size_t)MN + i4);
    float4 b  = *reinterpret_cast<const float4*>(bias + (i4 % N));
    a.x += p0.x + p1.x + b.x;
    a.y += p0.y + p1.y + b.y;
    a.z += p0.z + p1.z + b.z;
    a.w += p0.w + p1.w + b.w;
    *reinterpret_cast<float4*>(x + i4) = a;
}

// Fused: x_row += p0+p1+bias, then LayerNorm(x_row) -> bf16 out.
// Used for BOTH proj+ln2 and fc2+ln1(next). partf (scratch2) is disjoint
// from x and outb=hbuf (r14-verified aliasing).
__global__ __launch_bounds__(256) void reduce_ln_kernel(
    float* __restrict__ x, const float* __restrict__ p,
    const float* __restrict__ bias,
    const float* __restrict__ g, const float* __restrict__ beta,
    u16* __restrict__ outb, int nrows)
{
    int row = blockIdx.x * 4 + (threadIdx.x >> 6);
    if (row >= nrows) return;
    int lane = threadIdx.x & 63;
    size_t MN = (size_t)nrows * DD;
    float4 v[3];
    #pragma unroll
    for (int pp = 0; pp < 3; ++pp) {
        int d0 = pp * 256 + lane * 4;
        size_t ix = (size_t)row * DD + d0;
        float4 xv = *reinterpret_cast<const float4*>(x + ix);
        float4 p0 = *reinterpret_cast<const float4*>(p + ix);
        float4 p1 = *reinterpret_cast<const float4*>(p + MN + ix);
        float4 bv = *reinterpret_cast<const float4*>(bias + d0);
        xv.x += p0.x + p1.x + bv.x;
        xv.y += p0.y + p1.y + bv.y;
        xv.z += p0.z + p1.z + bv.z;
        xv.w += p0.w + p1.w + bv.w;
        *reinterpret_cast<float4*>(x + ix) = xv;
        v[pp] = xv;
    }
    float s = 0.f;
    #pragma unroll
    for (int pp = 0; pp < 3; ++pp) s += v[pp].x + v[pp].y + v[pp].z + v[pp].w;
    #pragma unroll
    for (int off = 32; off; off >>= 1) s += __shfl_xor(s, off);
    float mean = s * (1.f / 768.f);
    float q = 0.f;
    #pragma unroll
    for (int pp = 0; pp < 3; ++pp) {
        float a = v[pp].x - mean, b = v[pp].y - mean, c = v[pp].z - mean, d = v[pp].w - mean;
        q += a * a + b * b + c * c + d * d;
    }
    #pragma unroll
    for (int off = 32; off; off >>= 1) q += __shfl_xor(q, off);
    float rstd = rsqrtf(q * (1.f / 768.f) + 1e-5f);
    #pragma unroll
    for (int pp = 0; pp < 3; ++pp) {
        int d0 = pp * 256 + lane * 4;
        float4 gg = *reinterpret_cast<const float4*>(g + d0);
        float4 bb = *reinterpret_cast<const float4*>(beta + d0);
        u16x4 ob = { f2bf(gg.x * (v[pp].x - mean) * rstd + bb.x),
                     f2bf(gg.y * (v[pp].y - mean) * rstd + bb.y),
                     f2bf(gg.z * (v[pp].z - mean) * rstd + bb.z),
                     f2bf(gg.w * (v[pp].w - mean) * rstd + bb.w) };
        *reinterpret_cast<u16x4*>(outb + (size_t)row * DD + d0) = ob;
    }
}

__global__ void bias_edge_kernel(float* __restrict__ bias)
{
    int b = blockIdx.x, t = threadIdx.x;
    if (t < LL) {
        bias[((size_t)b * LL + 0) * LL + t] = 0.f;
        bias[((size_t)b * LL + t) * LL + 0] = 0.f;
    }
}

// ---------------------------------------------------------------------------
__global__ void combine_kernel(
    const float* __restrict__ toki, const float* __restrict__ tokm,
    const float* __restrict__ cls, const float* __restrict__ pos,
    float* __restrict__ x)
{
    size_t idx = (size_t)blockIdx.x * 256 + threadIdx.x;
    if (idx >= (size_t)MROWS * DD) return;
    int d = (int)(idx % DD);
    size_t bl = idx / DD;
    int l = (int)(bl % LL);
    int b = (int)(bl / LL);
    float v;
    if (l == 0) v = cls[d];
    else {
        size_t tix = ((size_t)b * NTOK + (l - 1)) * DD + d;
        v = toki[tix] + 0.5f * tokm[tix];
    }
    x[idx] = v + pos[(size_t)l * DD + d];
}

// ---------------------------------------------------------------------------
// LayerNorm: one wave per row, shfl-only. 4 rows/block.
// ---------------------------------------------------------------------------
template<int OUT>
__global__ __launch_bounds__(256) void ln_kernel(
    const float* __restrict__ in, const float* __restrict__ g,
    const float* __restrict__ beta, float* __restrict__ outf,
    u16* __restrict__ outb, int nrows)
{
    int row = blockIdx.x * 4 + (threadIdx.x >> 6);
    if (row >= nrows) return;
    int lane = threadIdx.x & 63;
    const float* xr = in + (size_t)row * DD;
    float4 v[3];
    #pragma unroll
    for (int p = 0; p < 3; ++p)
        v[p] = *reinterpret_cast<const float4*>(xr + p * 256 + lane * 4);
    float s = 0.f;
    #pragma unroll
    for (int p = 0; p < 3; ++p) s += v[p].x + v[p].y + v[p].z + v[p].w;
    #pragma unroll
    for (int off = 32; off; off >>= 1) s += __shfl_xor(s, off);
    float mean = s * (1.f / 768.f);
    float q = 0.f;
    #pragma unroll
    for (int p = 0; p < 3; ++p) {
        float a = v[p].x - mean, b = v[p].y - mean, c = v[p].z - mean, d = v[p].w - mean;
        q += a * a + b * b + c * c + d * d;
    }
    #pragma unroll
    for (int off = 32; off; off >>= 1) q += __shfl_xor(q, off);
    float rstd = rsqrtf(q * (1.f / 768.f) + 1e-5f);
    #pragma unroll
    for (int p = 0; p < 3; ++p) {
        int d0 = p * 256 + lane * 4;
        float4 gg = *reinterpret_cast<const float4*>(g + d0);
        float4 bb = *reinterpret_cast<const float4*>(beta + d0);
        float o0 = gg.x * (v[p].x - mean) * rstd + bb.x;
        float o1 = gg.y * (v[p].y - mean) * rstd + bb.y;
        float o2 = gg.z * (v[p].z - mean) * rstd + bb.z;
        float o3 = gg.w * (v[p].w - mean) * rstd + bb.w;
        if (OUT == 0 || OUT == 2) {
            float4 of = make_float4(o0, o1, o2, o3);
            *reinterpret_cast<float4*>(outf + (size_t)row * DD + d0) = of;
        }
        if (OUT == 1 || OUT == 2) {
            u16x4 ob = { f2bf(o0), f2bf(o1), f2bf(o2), f2bf(o3) };
            *reinterpret_cast<u16x4*>(outb + (size_t)row * DD + d0) = ob;
        }
    }
}

// ---------------------------------------------------------------------------
// MFMA attention — 8 waves (r12-verified)
// ---------------------------------------------------------------------------
constexpr int KSTRE = 72;
constexpr int VSTRE = 232;
constexpr int PSTRE = 232;

__global__ __launch_bounds__(512) void attn_mfma_kernel(
    const u16* __restrict__ qkv, const float* __restrict__ bias,
    u16* __restrict__ o)
{
    const int h = blockIdx.x, b = blockIdx.y;
    const int tid = threadIdx.x, wave = tid >> 6, lane = tid & 63;
    const int lo = lane & 15, hi = lane >> 4;

    __shared__ u16 Ks[208 * KSTRE];
    __shared__ u16 Vt[64 * VSTRE];
    __shared__ u16 Ps[8][16 * PSTRE];

    const u16* qb = qkv + (size_t)b * LL * 2304;

    for (int idx = tid; idx < 208 * 8; idx += 512) {
        int key = idx >> 3, c8 = idx & 7;
        u16x8 v = {};
        if (key < LL) v = *reinterpret_cast<const u16x8*>(qb + (size_t)key * 2304 + 768 + h * 64 + c8 * 8);
        *reinterpret_cast<u16x8*>(&Ks[key * KSTRE + c8 * 8]) = v;
    }
    for (int idx = tid; idx < 224 * 8; idx += 512) {
        int key = idx >> 3, c8 = idx & 7;
        u16x8 v = {};
        if (key < LL) v = *reinterpret_cast<const u16x8*>(qb + (size_t)key * 2304 + 1536 + h * 64 + c8 * 8);
        #pragma unroll
        for (int e = 0; e < 8; ++e) Vt[(c8 * 8 + e) * VSTRE + key] = v[e];
    }
    __syncthreads();

    u16* P = Ps[wave];
    const float* biasbb = bias + (size_t)b * LL * LL;

    for (int rt = wave; rt < 13; rt += 8) {
        int q = rt * 16 + lo; if (q > LL - 1) q = LL - 1;
        const u16* qrow = qb + (size_t)q * 2304 + h * 64;
        bf16x8 qa0 = *reinterpret_cast<const bf16x8*>(qrow + hi * 8);
        bf16x8 qa1 = *reinterpret_cast<const bf16x8*>(qrow + 32 + hi * 8);

        f32x4 st[13];
        #pragma unroll
        for (int t = 0; t < 13; ++t) {
            int keyc = t * 16 + lo;
            bf16x8 kb0 = *reinterpret_cast<const bf16x8*>(&Ks[keyc * KSTRE + hi * 8]);
            bf16x8 kb1 = *reinterpret_cast<const bf16x8*>(&Ks[keyc * KSTRE + 32 + hi * 8]);
            f32x4 a = {};
            a = __builtin_amdgcn_mfma_f32_16x16x32_bf16(qa0, kb0, a, 0, 0, 0);
            a = __builtin_amdgcn_mfma_f32_16x16x32_bf16(qa1, kb1, a, 0, 0, 0);
            st[t] = a;
        }

        #pragma unroll
        for (int r = 0; r < 4; ++r) {
            int qq = rt * 16 + hi * 4 + r;
            int qc = qq > LL - 1 ? LL - 1 : qq;
            const float* brow = biasbb + (size_t)qc * LL;
            float s[13];
            float m = -1e30f;
            #pragma unroll
            for (int t = 0; t < 13; ++t) {
                int col = t * 16 + lo;
                float v;
                if (col < LL) v = st[t][r] * 0.125f + brow[col];
                else          v = -1e30f;
                s[t] = v;
                m = fmaxf(m, v);
            }
            m = fmaxf(m, __shfl_xor(m, 1));
            m = fmaxf(m, __shfl_xor(m, 2));
            m = fmaxf(m, __shfl_xor(m, 4));
            m = fmaxf(m, __shfl_xor(m, 8));
            float sum = 0.f;
            #pragma unroll
            for (int t = 0; t < 13; ++t) { float e = __expf(s[t] - m); s[t] = e; sum += e; }
            sum += __shfl_xor(sum, 1);
            sum += __shfl_xor(sum, 2);
            sum += __shfl_xor(sum, 4);
            sum += __shfl_xor(sum, 8);
            float inv = 1.f / sum;
            int prow = (hi * 4 + r) * PSTRE;
            #pragma unroll
            for (int t = 0; t < 13; ++t) P[prow + t * 16 + lo] = f2bf(s[t] * inv);
            P[prow + 208 + lo] = 0;
        }

        f32x4 oacc[4] = {};
        #pragma unroll
        for (int kt = 0; kt < 7; ++kt) {
            bf16x8 pa = *reinterpret_cast<const bf16x8*>(&P[lo * PSTRE + kt * 32 + hi * 8]);
            #pragma unroll
            for (int dt = 0; dt < 4; ++dt) {
                bf16x8 vb = *reinterpret_cast<const bf16x8*>(&Vt[(dt * 16 + lo) * VSTRE + kt * 32 + hi * 8]);
                oacc[dt] = __builtin_amdgcn_mfma_f32_16x16x32_bf16(pa, vb, oacc[dt], 0, 0, 0);
            }
        }

        #pragma unroll
        for (int dt = 0; dt < 4; ++dt) {
            #pragma unroll
            for (int r = 0; r < 4; ++r) {
                int qq = rt * 16 + hi * 4 + r;
                if (qq < LL)
                    o[((size_t)(b * LL + qq)) * DD + h * 64 + dt * 16 + lo] = f2bf(oacc[dt][r]);
            }
        }
    }
}

// ---------------------------------------------------------------------------
__global__ __launch_bounds__(256) void final_kernel(
    const float* __restrict__ x,
    const float* __restrict__ eg, const float* __restrict__ eb,
    const float* __restrict__ fg, const float* __restrict__ fb,
    const float* __restrict__ hw, const float* __restrict__ hb,
    float* __restrict__ out)
{
    int b = blockIdx.x;
    int tid = threadIdx.x;
    __shared__ float xs[768];
    __shared__ float red[256];
    const float* xr = x + (size_t)b * LL * DD;
    #pragma unroll
    for (int r = 0; r < 3; ++r) xs[tid + r * 256] = xr[tid + r * 256];
    __syncthreads();
    for (int pass = 0; pass < 2; ++pass) {
        const float* g  = pass ? fg : eg;
        const float* bb = pass ? fb : eb;
        red[tid] = xs[tid] + xs[tid + 256] + xs[tid + 512];
        __syncthreads();
        for (int off = 128; off; off >>= 1) {
            if (tid < off) red[tid] += red[tid + off];
            __syncthreads();
        }
        float mean = red[0] * (1.f / 768.f);
        __syncthreads();
        float q = 0.f;
        #pragma unroll
        for (int r = 0; r < 3; ++r) { float dv = xs[tid + r * 256] - mean; q += dv * dv; }
        red[tid] = q;
        __syncthreads();
        for (int off = 128; off; off >>= 1) {
            if (tid < off) red[tid] += red[tid + off];
            __syncthreads();
        }
        float rstd = rsqrtf(red[0] * (1.f / 768.f) + 1e-5f);
        __syncthreads();
        #pragma unroll
        for (int r = 0; r < 3; ++r) {
            int d = tid + r * 256;
            xs[d] = g[d] * (xs[d] - mean) * rstd + bb[d];
        }
        __syncthreads();
    }
    int c = tid >> 6, lane = tid & 63;
    float part = 0.f;
    for (int d = lane; d < 768; d += 64) part += xs[d] * hw[c * 768 + d];
    #pragma unroll
    for (int off = 32; off; off >>= 1) part += __shfl_down(part, off);
    if (lane == 0) out[b * 4 + c] = part + hb[c];
}

// ---------------------------------------------------------------------------
extern "C" void kernel_launch(void* const* d_in, const int* in_sizes, int n_in,
                              void* d_out, int out_size, void* d_ws, size_t ws_size,
                              hipStream_t stream)
{
    const float* img    = (const float*)d_in[0];
    const float* mask   = (const float*)d_in[1];
    const float* pe_iw  = (const float*)d_in[2];
    const float* pe_ib  = (const float*)d_in[3];
    const float* pe_ig  = (const float*)d_in[4];
    const float* pe_ibb = (const float*)d_in[5];
    const float* pe_mw  = (const float*)d_in[6];
    const float* pe_mb  = (const float*)d_in[7];
    const float* pe_mg  = (const float*)d_in[8];
    const float* pe_mbb = (const float*)d_in[9];
    const float* cls    = (const float*)d_in[10];
    const float* pos    = (const float*)d_in[11];
    const float* ln1_g  = (const float*)d_in[12];
    const float* ln1_b  = (const float*)d_in[13];
    const float* w_qkv  = (const float*)d_in[14];
    const float* b_qkv  = (const float*)d_in[15];
    const float* w_out  = (const float*)d_in[16];
    const float* b_out  = (const float*)d_in[17];
    const float* ln2_g  = (const float*)d_in[18];
    const float* ln2_b  = (const float*)d_in[19];
    const float* w_fc1  = (const float*)d_in[20];
    const float* b_fc1  = (const float*)d_in[21];
    const float* w_fc2  = (const float*)d_in[22];
    const float* b_fc2  = (const float*)d_in[23];
    const float* enc_g  = (const float*)d_in[24];
    const float* enc_b  = (const float*)d_in[25];
    const float* fin_g  = (const float*)d_in[26];
    const float* fin_b  = (const float*)d_in[27];
    const float* head_w = (const float*)d_in[28];
    const float* head_b = (const float*)d_in[29];

    char* wsb = (char*)d_ws;
    size_t off = 0;
    auto alloc = [&](size_t bytes) { void* p = wsb + off; off += (bytes + 255) & ~(size_t)255; return p; };

    float* x     = (float*)alloc((size_t)MROWS * DD * 4);
    u16*   qkvb  = (u16*)  alloc((size_t)MROWS * 3 * DD * 2);
    u16*   hbuf  = (u16*)  alloc((size_t)MROWS * DD * 2);
    u16*   fc1b  = (u16*)  alloc((size_t)MROWS * 4 * DD * 2);
    float* biasb = (float*)alloc((size_t)BB * LL * LL * 4);
    u16*   wqb   = (u16*)  alloc((size_t)3 * DD * DD * 2);
    u16*   wob   = (u16*)  alloc((size_t)DD * DD * 2);
    u16*   w1b   = (u16*)  alloc((size_t)4 * DD * DD * 2);
    u16*   w2b   = (u16*)  alloc((size_t)4 * DD * DD * 2);
    // scratch2 union: toki+tokm during setup / split-K partials during loop
    float* scratch2 = (float*)alloc((size_t)2 * MROWS * DD * 4);
    float* toki  = scratch2;
    float* tokm  = scratch2 + (size_t)MTOK * DD;
    float* partf = scratch2;
    u16*   pa    = fc1b;
    float* ttmp  = (float*)qkvb;
    u16*   tokmb = hbuf;

    // ---- patch embed (img) ----
    cast_kernel<<<(DD * DD / 4 + 255) / 256, 256, 0, stream>>>(pe_iw, wob, DD * DD);
    patchify_kernel<<<(MTOK * DD + 255) / 256, 256, 0, stream>>>(img, 3, pa, MTOK * DD);
    gemm_bf16<0><<<dim3(DD / 128, (MTOK + 255) / 256), 512, 0, stream>>>(
        pa, wob, pe_ib, nullptr, ttmp, MTOK, DD, DD, 0);
    ln_kernel<0><<<MTOK / 4, 256, 0, stream>>>(ttmp, pe_ig, pe_ibb, toki, nullptr, MTOK);

    // ---- patch embed (mask) ----
    cast_kernel<<<(DD * 256 / 4 + 255) / 256, 256, 0, stream>>>(pe_mw, wob, DD * 256);
    patchify_kernel<<<(MTOK * 256 + 255) / 256, 256, 0, stream>>>(mask, 1, pa, MTOK * 256);
    gemm_bf16<0><<<dim3(DD / 128, (MTOK + 255) / 256), 512, 0, stream>>>(
        pa, wob, pe_mb, nullptr, ttmp, MTOK, DD, 256, 0);
    ln_kernel<2><<<MTOK / 4, 256, 0, stream>>>(ttmp, pe_mg, pe_mbb, tokm, tokmb, MTOK);

    // ---- attention bias ----
    gemm_bf16<3><<<dim3(2, 1, BB), 512, 0, stream>>>(
        tokmb, tokmb, nullptr, nullptr, biasb, NTOK, NTOK, DD, (long long)NTOK * DD);
    bias_edge_kernel<<<BB, 256, 0, stream>>>(biasb);

    // ---- combine + layer-0 ln1 ----
    combine_kernel<<<(MROWS * DD + 255) / 256, 256, 0, stream>>>(toki, tokm, cls, pos, x);
    ln_kernel<1><<<MROWS / 4, 256, 0, stream>>>(x, ln1_g, ln1_b, nullptr, hbuf, MROWS);

    const int mblk = (MROWS + 255) / 256;   // 25
    const int MN = MROWS * DD;
    const int wqn = 3 * DD * DD, won = DD * DD, w1n = 4 * DD * DD, w2n = 4 * DD * DD;
    const int castTot = (wqn + won + w1n + w2n) / 4;
    for (int l = 0; l < 12; ++l) {
        cast4_kernel<<<(castTot + 255) / 256, 256, 0, stream>>>(
            w_qkv + (size_t)l * wqn, wqn, w_out + (size_t)l * won, won,
            w_fc1 + (size_t)l * w1n, w1n, w_fc2 + (size_t)l * w2n, w2n,
            wqb, wob, w1b, w2b);
        gemm_bf16<4><<<dim3(3 * DD / 128, mblk), 512, 0, stream>>>(
            hbuf, wqb, b_qkv + l * 3 * DD, nullptr, qkvb, MROWS, 3 * DD, DD, 0);
        attn_mfma_kernel<<<dim3(HH, BB), 512, 0, stream>>>(qkvb, biasb, hbuf);
        // proj split-K=2 (K=768 -> 384 each, 300 blocks) + fused res-add+ln2
        gemm_bf16<5><<<dim3(DD / 128, mblk, 2), 512, 0, stream>>>(
            hbuf, wob, nullptr, nullptr, partf, MROWS, DD, DD, 0);
        reduce_ln_kernel<<<MROWS / 4, 256, 0, stream>>>(
            x, partf, b_out + l * DD, ln2_g + l * DD, ln2_b + l * DD, hbuf, MROWS);
        gemm_bf16<1><<<dim3(4 * DD / 128, mblk), 512, 0, stream>>>(
            hbuf, w1b, b_fc1 + l * 4 * DD, nullptr, fc1b, MROWS, 4 * DD, DD, 0);
        gemm_bf16<5><<<dim3(DD / 128, mblk, 2), 512, 0, stream>>>(
            fc1b, w2b, nullptr, nullptr, partf, MROWS, DD, 4 * DD, 0);
        if (l < 11) {
            reduce_ln_kernel<<<MROWS / 4, 256, 0, stream>>>(
                x, partf, b_fc2 + l * DD, ln1_g + (l + 1) * DD, ln1_b + (l + 1) * DD,
                hbuf, MROWS);
        } else {
            splitk_reduce_kernel<<<(MN / 4 + 255) / 256, 256, 0, stream>>>(
                x, partf, b_fc2 + l * DD, MN, DD);
        }
    }
    final_kernel<<<BB, 256, 0, stream>>>(x, enc_g, enc_b, fin_g, fin_b, head_w, head_b, (float*)d_out);
}

// Round 17
// 3168.686 us; speedup vs baseline: 1.0240x; 1.0240x over previous
//
#include <hip/hip_runtime.h>
#include <hip/hip_bf16.h>
#include <math.h>

typedef unsigned int   u32;
typedef unsigned short u16;
typedef __bf16 bf16x8 __attribute__((ext_vector_type(8)));
typedef float  f32x4  __attribute__((ext_vector_type(4)));
typedef u16    u16x8  __attribute__((ext_vector_type(8)));
typedef u16    u16x4  __attribute__((ext_vector_type(4)));

constexpr int BB = 32, DD = 768, LL = 197, HH = 12, NTOK = 196;
constexpr int MROWS = BB * LL;        // 6304
constexpr int MTOK  = BB * NTOK;      // 6272
constexpr long long LLDD = (long long)LL * DD;

__device__ __forceinline__ u16 f2bf(float f) {
    union { float f; u32 u; } v; v.f = f;
    u32 r = v.u + 0x7fff + ((v.u >> 16) & 1);
    return (u16)(r >> 16);
}
__device__ __forceinline__ float bf2f(u16 u) {
    union { u32 u; float f; } v; v.u = ((u32)u) << 16;
    return v.f;
}

#define AS1 __attribute__((address_space(1)))
#define AS3 __attribute__((address_space(3)))
__device__ __forceinline__ void gload_lds16(const void* g, void* l) {
    __builtin_amdgcn_global_load_lds((const AS1 u32*)g, (AS3 u32*)l, 16, 0, 0);
}

// ---------------------------------------------------------------------------
__global__ void cast_kernel(const float* __restrict__ in, u16* __restrict__ out, int n)
{
    int i4 = (blockIdx.x * 256 + threadIdx.x) * 4;
    if (i4 >= n) return;
    float4 v = *reinterpret_cast<const float4*>(in + i4);
    out[i4]   = f2bf(v.x); out[i4+1] = f2bf(v.y);
    out[i4+2] = f2bf(v.z); out[i4+3] = f2bf(v.w);
}

__global__ void cast4_kernel(const float* s0, int n0, const float* s1, int n1,
                             const float* s2, int n2, const float* s3, int n3,
                             u16* d0, u16* d1, u16* d2, u16* d3)
{
    int i4 = (blockIdx.x * 256 + threadIdx.x) * 4;
    const float* s; u16* d; int off;
    if      (i4 < n0)            { s = s0; d = d0; off = i4; }
    else if (i4 < n0+n1)         { s = s1; d = d1; off = i4 - n0; }
    else if (i4 < n0+n1+n2)      { s = s2; d = d2; off = i4 - n0 - n1; }
    else if (i4 < n0+n1+n2+n3)   { s = s3; d = d3; off = i4 - n0 - n1 - n2; }
    else return;
    float4 v = *reinterpret_cast<const float4*>(s + off);
    d[off]   = f2bf(v.x); d[off+1] = f2bf(v.y);
    d[off+2] = f2bf(v.z); d[off+3] = f2bf(v.w);
}

// ---------------------------------------------------------------------------
__global__ void patchify_kernel(const float* __restrict__ src, int C,
                                u16* __restrict__ out, int total)
{
    int idx = blockIdx.x * 256 + threadIdx.x;
    if (idx >= total) return;
    int K = C * 256;
    int row = idx / K, k = idx % K;
    int b = row / NTOK, n = row % NTOK;
    int c = k >> 8, rem = k & 255, pi = rem >> 4, pj = rem & 15;
    int i14 = n / 14, j14 = n % 14;
    float v = src[(((size_t)b * C + c) * 224 + i14 * 16 + pi) * 224 + j14 * 16 + pj];
    out[idx] = f2bf(v);
}

// ---------------------------------------------------------------------------
// bf16 MFMA GEMM — 256x128 tile, 8 waves, BK=32, single-barrier dbuf,
// XOR-swizzled conflict-free staging (r15/r16-verified).
// rsA = element stride between consecutive M-rows of A (K for compact).
// rsC = element stride between consecutive M-rows of C/res (N for compact).
// Used by the layer-11 CLS-only tail (rows at stride LL*DD).
// MODE 0: f32 +bias   MODE 1: GELU->bf16 +bias   MODE 2: f32 +bias+res
// MODE 3: batched bias-GEMM   MODE 4: bf16 +bias
// MODE 5: split-K=2, raw f32 partial store to Cout + z*M*rsC (no bias)
// ---------------------------------------------------------------------------
template<int MODE>
__global__ __launch_bounds__(512) void gemm_bf16(
    const u16* __restrict__ A, const u16* __restrict__ W,
    const float* __restrict__ bias, const float* __restrict__ res,
    void* __restrict__ Cout, int M, int N, int K, long long strideA,
    long long rsA, long long rsC)
{
    __shared__ u16 As[2][8192];   // 256 rows x 32 k
    __shared__ u16 Bs[2][4096];   // 128 rows x 32 k
    const int tid  = threadIdx.x;
    const int wave = tid >> 6, lane = tid & 63;
    const int lo = lane & 15, hi = lane >> 4;
    const int wr = wave >> 1, wc = wave & 1;

    const int m0 = blockIdx.y * 256, n0 = blockIdx.x * 128;
    if (MODE == 3) { A += blockIdx.z * strideA; W += blockIdx.z * strideA; }

    const int Klen = (MODE == 5) ? (K >> 1) : K;
    const int kb   = (MODE == 5) ? blockIdx.z * Klen : 0;

    const int limA = M - 1;
    const int limB = (MODE == 3 ? M : N) - 1;
    const int srow = lane >> 2;
    const int scol = ((lane & 3) ^ ((lane >> 3) & 3)) << 3;
    int ra0 = m0 + wave * 16 + srow;        if (ra0 > limA) ra0 = limA;
    int ra1 = m0 + 128 + wave * 16 + srow;  if (ra1 > limA) ra1 = limA;
    int rb0 = n0 + wave * 16 + srow;        if (rb0 > limB) rb0 = limB;
    const u16* Arow0 = A + (size_t)ra0 * rsA + kb + scol;
    const u16* Arow1 = A + (size_t)ra1 * rsA + kb + scol;
    const u16* Brow0 = W + (size_t)rb0 * K + kb + scol;

    const int fro = lo * 32 + ((hi ^ ((lo >> 1) & 3)) << 3);

    f32x4 acc[4][4] = {};

    #define STAGE(bf_, k0_)                                         \
        do {                                                        \
            gload_lds16(Arow0 + (k0_), &As[bf_][wave * 512]);       \
            gload_lds16(Arow1 + (k0_), &As[bf_][4096 + wave * 512]);\
            gload_lds16(Brow0 + (k0_), &Bs[bf_][wave * 512]);       \
        } while (0)

    #define COMPUTE(bf_)                                                         \
        do {                                                                     \
            bf16x8 af[4], bfr[4];                                                \
            _Pragma("unroll")                                                    \
            for (int i = 0; i < 4; ++i)                                          \
                af[i] = *reinterpret_cast<const bf16x8*>(                        \
                    &As[bf_][(wr * 4 + i) * 512 + fro]);                         \
            _Pragma("unroll")                                                    \
            for (int j = 0; j < 4; ++j)                                          \
                bfr[j] = *reinterpret_cast<const bf16x8*>(                       \
                    &Bs[bf_][(wc * 4 + j) * 512 + fro]);                         \
            _Pragma("unroll")                                                    \
            for (int i = 0; i < 4; ++i)                                          \
                _Pragma("unroll")                                                \
                for (int j = 0; j < 4; ++j)                                      \
                    acc[i][j] = __builtin_amdgcn_mfma_f32_16x16x32_bf16(         \
                        af[i], bfr[j], acc[i][j], 0, 0, 0);                      \
        } while (0)

    const int nt = Klen >> 5;   // even at all call sites
    STAGE(0, 0);
    __syncthreads();
    int t = 0;
    for (; t + 2 < nt; t += 2) {
        STAGE(1, (t + 1) * 32);
        COMPUTE(0);
        __syncthreads();
        STAGE(0, (t + 2) * 32);
        COMPUTE(1);
        __syncthreads();
    }
    STAGE(1, (t + 1) * 32);
    COMPUTE(0);
    __syncthreads();
    COMPUTE(1);
    #undef STAGE
    #undef COMPUTE

    const size_t zoff = (MODE == 5) ? (size_t)blockIdx.z * M * rsC : 0;
    const int cr = hi * 4;
    const int cc = lo;
    #pragma unroll
    for (int i = 0; i < 4; ++i) {
        #pragma unroll
        for (int r = 0; r < 4; ++r) {
            int m = m0 + wr * 64 + i * 16 + cr + r;
            if (MODE != 3 && m >= M) continue;
            #pragma unroll
            for (int j = 0; j < 4; ++j) {
                int n = n0 + wc * 64 + j * 16 + cc;
                float v = acc[i][j][r];
                if (MODE == 0) {
                    ((float*)Cout)[(size_t)m * rsC + n] = v + bias[n];
                } else if (MODE == 1) {
                    float t2 = v + bias[n];
                    t2 = 0.5f * t2 * (1.f + erff(t2 * 0.70710678118654752f));
                    ((u16*)Cout)[(size_t)m * rsC + n] = f2bf(t2);
                } else if (MODE == 2) {
                    ((float*)Cout)[(size_t)m * rsC + n] = v + bias[n] + res[(size_t)m * rsC + n];
                } else if (MODE == 4) {
                    ((u16*)Cout)[(size_t)m * rsC + n] = f2bf(v + bias[n]);
                } else if (MODE == 5) {
                    ((float*)Cout)[zoff + (size_t)m * rsC + n] = v;
                } else { // MODE 3
                    if (m < M && n < M) {
                        float* C3 = (float*)Cout + (size_t)blockIdx.z * LL * LL;
                        C3[(size_t)(m + 1) * LL + (n + 1)] = v * 0.03608439182435161f;
                    }
                }
            }
        }
    }
}

// x[i] += p0[i] + p1[i] + bias[i % N]   (split-K reduce, N % 4 == 0)
__global__ void splitk_reduce_kernel(float* __restrict__ x, const float* __restrict__ p,
                                     const float* __restrict__ bias, int MN, int N)
{
    int i4 = (blockIdx.x * 256 + threadIdx.x) * 4;
    if (i4 >= MN) return;
    float4 a  = *reinterpret_cast<const float4*>(x + i4);
    float4 p0 = *reinterpret_cast<const float4*>(p + i4);
    float4 p1 = *reinterpret_cast<const float4*>(p + (size_t)MN + i4);
    float4 b  = *reinterpret_cast<const float4*>(bias + (i4 % N));
    a.x += p0.x + p1.x + b.x;
    a.y += p0.y + p1.y + b.y;
    a.z += p0.z + p1.z + b.z;
    a.w += p0.w + p1.w + b.w;
    *reinterpret_cast<float4*>(x + i4) = a;
}

// Fused: x_row += p0+p1+bias, then LayerNorm(x_row) -> bf16 out.
// partf (scratch2) is disjoint from x and outb=hbuf (r14-verified).
__global__ __launch_bounds__(256) void reduce_ln_kernel(
    float* __restrict__ x, const float* __restrict__ p,
    const float* __restrict__ bias,
    const float* __restrict__ g, const float* __restrict__ beta,
    u16* __restrict__ outb, int nrows)
{
    int row = blockIdx.x * 4 + (threadIdx.x >> 6);
    if (row >= nrows) return;
    int lane = threadIdx.x & 63;
    size_t MN = (size_t)nrows * DD;
    float4 v[3];
    #pragma unroll
    for (int pp = 0; pp < 3; ++pp) {
        int d0 = pp * 256 + lane * 4;
        size_t ix = (size_t)row * DD + d0;
        float4 xv = *reinterpret_cast<const float4*>(x + ix);
        float4 p0 = *reinterpret_cast<const float4*>(p + ix);
        float4 p1 = *reinterpret_cast<const float4*>(p + MN + ix);
        float4 bv = *reinterpret_cast<const float4*>(bias + d0);
        xv.x += p0.x + p1.x + bv.x;
        xv.y += p0.y + p1.y + bv.y;
        xv.z += p0.z + p1.z + bv.z;
        xv.w += p0.w + p1.w + bv.w;
        *reinterpret_cast<float4*>(x + ix) = xv;
        v[pp] = xv;
    }
    float s = 0.f;
    #pragma unroll
    for (int pp = 0; pp < 3; ++pp) s += v[pp].x + v[pp].y + v[pp].z + v[pp].w;
    #pragma unroll
    for (int off = 32; off; off >>= 1) s += __shfl_xor(s, off);
    float mean = s * (1.f / 768.f);
    float q = 0.f;
    #pragma unroll
    for (int pp = 0; pp < 3; ++pp) {
        float a = v[pp].x - mean, b = v[pp].y - mean, c = v[pp].z - mean, d = v[pp].w - mean;
        q += a * a + b * b + c * c + d * d;
    }
    #pragma unroll
    for (int off = 32; off; off >>= 1) q += __shfl_xor(q, off);
    float rstd = rsqrtf(q * (1.f / 768.f) + 1e-5f);
    #pragma unroll
    for (int pp = 0; pp < 3; ++pp) {
        int d0 = pp * 256 + lane * 4;
        float4 gg = *reinterpret_cast<const float4*>(g + d0);
        float4 bb = *reinterpret_cast<const float4*>(beta + d0);
        u16x4 ob = { f2bf(gg.x * (v[pp].x - mean) * rstd + bb.x),
                     f2bf(gg.y * (v[pp].y - mean) * rstd + bb.y),
                     f2bf(gg.z * (v[pp].z - mean) * rstd + bb.z),
                     f2bf(gg.w * (v[pp].w - mean) * rstd + bb.w) };
        *reinterpret_cast<u16x4*>(outb + (size_t)row * DD + d0) = ob;
    }
}

__global__ void bias_edge_kernel(float* __restrict__ bias)
{
    int b = blockIdx.x, t = threadIdx.x;
    if (t < LL) {
        bias[((size_t)b * LL + 0) * LL + t] = 0.f;
        bias[((size_t)b * LL + t) * LL + 0] = 0.f;
    }
}

// ---------------------------------------------------------------------------
__global__ void combine_kernel(
    const float* __restrict__ toki, const float* __restrict__ tokm,
    const float* __restrict__ cls, const float* __restrict__ pos,
    float* __restrict__ x)
{
    size_t idx = (size_t)blockIdx.x * 256 + threadIdx.x;
    if (idx >= (size_t)MROWS * DD) return;
    int d = (int)(idx % DD);
    size_t bl = idx / DD;
    int l = (int)(bl % LL);
    int b = (int)(bl / LL);
    float v;
    if (l == 0) v = cls[d];
    else {
        size_t tix = ((size_t)b * NTOK + (l - 1)) * DD + d;
        v = toki[tix] + 0.5f * tokm[tix];
    }
    x[idx] = v + pos[(size_t)l * DD + d];
}

// ---------------------------------------------------------------------------
// LayerNorm: one wave per row, shfl-only, 4 rows/block.
// inStride = element stride between input rows (DD for compact; LL*DD for
// the layer-11 CLS gather). Outputs are compact at row*DD.
// ---------------------------------------------------------------------------
template<int OUT>
__global__ __launch_bounds__(256) void ln_kernel(
    const float* __restrict__ in, const float* __restrict__ g,
    const float* __restrict__ beta, float* __restrict__ outf,
    u16* __restrict__ outb, int nrows, long long inStride)
{
    int row = blockIdx.x * 4 + (threadIdx.x >> 6);
    if (row >= nrows) return;
    int lane = threadIdx.x & 63;
    const float* xr = in + (size_t)row * inStride;
    float4 v[3];
    #pragma unroll
    for (int p = 0; p < 3; ++p)
        v[p] = *reinterpret_cast<const float4*>(xr + p * 256 + lane * 4);
    float s = 0.f;
    #pragma unroll
    for (int p = 0; p < 3; ++p) s += v[p].x + v[p].y + v[p].z + v[p].w;
    #pragma unroll
    for (int off = 32; off; off >>= 1) s += __shfl_xor(s, off);
    float mean = s * (1.f / 768.f);
    float q = 0.f;
    #pragma unroll
    for (int p = 0; p < 3; ++p) {
        float a = v[p].x - mean, b = v[p].y - mean, c = v[p].z - mean, d = v[p].w - mean;
        q += a * a + b * b + c * c + d * d;
    }
    #pragma unroll
    for (int off = 32; off; off >>= 1) q += __shfl_xor(q, off);
    float rstd = rsqrtf(q * (1.f / 768.f) + 1e-5f);
    #pragma unroll
    for (int p = 0; p < 3; ++p) {
        int d0 = p * 256 + lane * 4;
        float4 gg = *reinterpret_cast<const float4*>(g + d0);
        float4 bb = *reinterpret_cast<const float4*>(beta + d0);
        float o0 = gg.x * (v[p].x - mean) * rstd + bb.x;
        float o1 = gg.y * (v[p].y - mean) * rstd + bb.y;
        float o2 = gg.z * (v[p].z - mean) * rstd + bb.z;
        float o3 = gg.w * (v[p].w - mean) * rstd + bb.w;
        if (OUT == 0 || OUT == 2) {
            float4 of = make_float4(o0, o1, o2, o3);
            *reinterpret_cast<float4*>(outf + (size_t)row * DD + d0) = of;
        }
        if (OUT == 1 || OUT == 2) {
            u16x4 ob = { f2bf(o0), f2bf(o1), f2bf(o2), f2bf(o3) };
            *reinterpret_cast<u16x4*>(outb + (size_t)row * DD + d0) = ob;
        }
    }
}

// ---------------------------------------------------------------------------
// MFMA attention — 8 waves (r12-verified)
// ---------------------------------------------------------------------------
constexpr int KSTRE = 72;
constexpr int VSTRE = 232;
constexpr int PSTRE = 232;

__global__ __launch_bounds__(512) void attn_mfma_kernel(
    const u16* __restrict__ qkv, const float* __restrict__ bias,
    u16* __restrict__ o)
{
    const int h = blockIdx.x, b = blockIdx.y;
    const int tid = threadIdx.x, wave = tid >> 6, lane = tid & 63;
    const int lo = lane & 15, hi = lane >> 4;

    __shared__ u16 Ks[208 * KSTRE];
    __shared__ u16 Vt[64 * VSTRE];
    __shared__ u16 Ps[8][16 * PSTRE];

    const u16* qb = qkv + (size_t)b * LL * 2304;

    for (int idx = tid; idx < 208 * 8; idx += 512) {
        int key = idx >> 3, c8 = idx & 7;
        u16x8 v = {};
        if (key < LL) v = *reinterpret_cast<const u16x8*>(qb + (size_t)key * 2304 + 768 + h * 64 + c8 * 8);
        *reinterpret_cast<u16x8*>(&Ks[key * KSTRE + c8 * 8]) = v;
    }
    for (int idx = tid; idx < 224 * 8; idx += 512) {
        int key = idx >> 3, c8 = idx & 7;
        u16x8 v = {};
        if (key < LL) v = *reinterpret_cast<const u16x8*>(qb + (size_t)key * 2304 + 1536 + h * 64 + c8 * 8);
        #pragma unroll
        for (int e = 0; e < 8; ++e) Vt[(c8 * 8 + e) * VSTRE + key] = v[e];
    }
    __syncthreads();

    u16* P = Ps[wave];
    const float* biasbb = bias + (size_t)b * LL * LL;

    for (int rt = wave; rt < 13; rt += 8) {
        int q = rt * 16 + lo; if (q > LL - 1) q = LL - 1;
        const u16* qrow = qb + (size_t)q * 2304 + h * 64;
        bf16x8 qa0 = *reinterpret_cast<const bf16x8*>(qrow + hi * 8);
        bf16x8 qa1 = *reinterpret_cast<const bf16x8*>(qrow + 32 + hi * 8);

        f32x4 st[13];
        #pragma unroll
        for (int t = 0; t < 13; ++t) {
            int keyc = t * 16 + lo;
            bf16x8 kb0 = *reinterpret_cast<const bf16x8*>(&Ks[keyc * KSTRE + hi * 8]);
            bf16x8 kb1 = *reinterpret_cast<const bf16x8*>(&Ks[keyc * KSTRE + 32 + hi * 8]);
            f32x4 a = {};
            a = __builtin_amdgcn_mfma_f32_16x16x32_bf16(qa0, kb0, a, 0, 0, 0);
            a = __builtin_amdgcn_mfma_f32_16x16x32_bf16(qa1, kb1, a, 0, 0, 0);
            st[t] = a;
        }

        #pragma unroll
        for (int r = 0; r < 4; ++r) {
            int qq = rt * 16 + hi * 4 + r;
            int qc = qq > LL - 1 ? LL - 1 : qq;
            const float* brow = biasbb + (size_t)qc * LL;
            float s[13];
            float m = -1e30f;
            #pragma unroll
            for (int t = 0; t < 13; ++t) {
                int col = t * 16 + lo;
                float v;
                if (col < LL) v = st[t][r] * 0.125f + brow[col];
                else          v = -1e30f;
                s[t] = v;
                m = fmaxf(m, v);
            }
            m = fmaxf(m, __shfl_xor(m, 1));
            m = fmaxf(m, __shfl_xor(m, 2));
            m = fmaxf(m, __shfl_xor(m, 4));
            m = fmaxf(m, __shfl_xor(m, 8));
            float sum = 0.f;
            #pragma unroll
            for (int t = 0; t < 13; ++t) { float e = __expf(s[t] - m); s[t] = e; sum += e; }
            sum += __shfl_xor(sum, 1);
            sum += __shfl_xor(sum, 2);
            sum += __shfl_xor(sum, 4);
            sum += __shfl_xor(sum, 8);
            float inv = 1.f / sum;
            int prow = (hi * 4 + r) * PSTRE;
            #pragma unroll
            for (int t = 0; t < 13; ++t) P[prow + t * 16 + lo] = f2bf(s[t] * inv);
            P[prow + 208 + lo] = 0;
        }

        f32x4 oacc[4] = {};
        #pragma unroll
        for (int kt = 0; kt < 7; ++kt) {
            bf16x8 pa = *reinterpret_cast<const bf16x8*>(&P[lo * PSTRE + kt * 32 + hi * 8]);
            #pragma unroll
            for (int dt = 0; dt < 4; ++dt) {
                bf16x8 vb = *reinterpret_cast<const bf16x8*>(&Vt[(dt * 16 + lo) * VSTRE + kt * 32 + hi * 8]);
                oacc[dt] = __builtin_amdgcn_mfma_f32_16x16x32_bf16(pa, vb, oacc[dt], 0, 0, 0);
            }
        }

        #pragma unroll
        for (int dt = 0; dt < 4; ++dt) {
            #pragma unroll
            for (int r = 0; r < 4; ++r) {
                int qq = rt * 16 + hi * 4 + r;
                if (qq < LL)
                    o[((size_t)(b * LL + qq)) * DD + h * 64 + dt * 16 + lo] = f2bf(oacc[dt][r]);
            }
        }
    }
}

// ---------------------------------------------------------------------------
__global__ __launch_bounds__(256) void final_kernel(
    const float* __restrict__ x,
    const float* __restrict__ eg, const float* __restrict__ eb,
    const float* __restrict__ fg, const float* __restrict__ fb,
    const float* __restrict__ hw, const float* __restrict__ hb,
    float* __restrict__ out)
{
    int b = blockIdx.x;
    int tid = threadIdx.x;
    __shared__ float xs[768];
    __shared__ float red[256];
    const float* xr = x + (size_t)b * LL * DD;
    #pragma unroll
    for (int r = 0; r < 3; ++r) xs[tid + r * 256] = xr[tid + r * 256];
    __syncthreads();
    for (int pass = 0; pass < 2; ++pass) {
        const float* g  = pass ? fg : eg;
        const float* bb = pass ? fb : eb;
        red[tid] = xs[tid] + xs[tid + 256] + xs[tid + 512];
        __syncthreads();
        for (int off = 128; off; off >>= 1) {
            if (tid < off) red[tid] += red[tid + off];
            __syncthreads();
        }
        float mean = red[0] * (1.f / 768.f);
        __syncthreads();
        float q = 0.f;
        #pragma unroll
        for (int r = 0; r < 3; ++r) { float dv = xs[tid + r * 256] - mean; q += dv * dv; }
        red[tid] = q;
        __syncthreads();
        for (int off = 128; off; off >>= 1) {
            if (tid < off) red[tid] += red[tid + off];
            __syncthreads();
        }
        float rstd = rsqrtf(red[0] * (1.f / 768.f) + 1e-5f);
        __syncthreads();
        #pragma unroll
        for (int r = 0; r < 3; ++r) {
            int d = tid + r * 256;
            xs[d] = g[d] * (xs[d] - mean) * rstd + bb[d];
        }
        __syncthreads();
    }
    int c = tid >> 6, lane = tid & 63;
    float part = 0.f;
    for (int d = lane; d < 768; d += 64) part += xs[d] * hw[c * 768 + d];
    #pragma unroll
    for (int off = 32; off; off >>= 1) part += __shfl_down(part, off);
    if (lane == 0) out[b * 4 + c] = part + hb[c];
}

// ---------------------------------------------------------------------------
extern "C" void kernel_launch(void* const* d_in, const int* in_sizes, int n_in,
                              void* d_out, int out_size, void* d_ws, size_t ws_size,
                              hipStream_t stream)
{
    const float* img    = (const float*)d_in[0];
    const float* mask   = (const float*)d_in[1];
    const float* pe_iw  = (const float*)d_in[2];
    const float* pe_ib  = (const float*)d_in[3];
    const float* pe_ig  = (const float*)d_in[4];
    const float* pe_ibb = (const float*)d_in[5];
    const float* pe_mw  = (const float*)d_in[6];
    const float* pe_mb  = (const float*)d_in[7];
    const float* pe_mg  = (const float*)d_in[8];
    const float* pe_mbb = (const float*)d_in[9];
    const float* cls    = (const float*)d_in[10];
    const float* pos    = (const float*)d_in[11];
    const float* ln1_g  = (const float*)d_in[12];
    const float* ln1_b  = (const float*)d_in[13];
    const float* w_qkv  = (const float*)d_in[14];
    const float* b_qkv  = (const float*)d_in[15];
    const float* w_out  = (const float*)d_in[16];
    const float* b_out  = (const float*)d_in[17];
    const float* ln2_g  = (const float*)d_in[18];
    const float* ln2_b  = (const float*)d_in[19];
    const float* w_fc1  = (const float*)d_in[20];
    const float* b_fc1  = (const float*)d_in[21];
    const float* w_fc2  = (const float*)d_in[22];
    const float* b_fc2  = (const float*)d_in[23];
    const float* enc_g  = (const float*)d_in[24];
    const float* enc_b  = (const float*)d_in[25];
    const float* fin_g  = (const float*)d_in[26];
    const float* fin_b  = (const float*)d_in[27];
    const float* head_w = (const float*)d_in[28];
    const float* head_b = (const float*)d_in[29];

    char* wsb = (char*)d_ws;
    size_t off = 0;
    auto alloc = [&](size_t bytes) { void* p = wsb + off; off += (bytes + 255) & ~(size_t)255; return p; };

    float* x     = (float*)alloc((size_t)MROWS * DD * 4);
    u16*   qkvb  = (u16*)  alloc((size_t)MROWS * 3 * DD * 2);
    u16*   hbuf  = (u16*)  alloc((size_t)MROWS * DD * 2);
    u16*   fc1b  = (u16*)  alloc((size_t)MROWS * 4 * DD * 2);
    float* biasb = (float*)alloc((size_t)BB * LL * LL * 4);
    u16*   wqb   = (u16*)  alloc((size_t)3 * DD * DD * 2);
    u16*   wob   = (u16*)  alloc((size_t)DD * DD * 2);
    u16*   w1b   = (u16*)  alloc((size_t)4 * DD * DD * 2);
    u16*   w2b   = (u16*)  alloc((size_t)4 * DD * DD * 2);
    // scratch2 union: toki+tokm during setup / split-K partials during loop
    float* scratch2 = (float*)alloc((size_t)2 * MROWS * DD * 4);
    float* toki  = scratch2;
    float* tokm  = scratch2 + (size_t)MTOK * DD;
    float* partf = scratch2;
    u16*   pa    = fc1b;
    float* ttmp  = (float*)qkvb;
    u16*   tokmb = hbuf;

    // ---- patch embed (img) ----
    cast_kernel<<<(DD * DD / 4 + 255) / 256, 256, 0, stream>>>(pe_iw, wob, DD * DD);
    patchify_kernel<<<(MTOK * DD + 255) / 256, 256, 0, stream>>>(img, 3, pa, MTOK * DD);
    gemm_bf16<0><<<dim3(DD / 128, (MTOK + 255) / 256), 512, 0, stream>>>(
        pa, wob, pe_ib, nullptr, ttmp, MTOK, DD, DD, 0, DD, DD);
    ln_kernel<0><<<MTOK / 4, 256, 0, stream>>>(ttmp, pe_ig, pe_ibb, toki, nullptr, MTOK, DD);

    // ---- patch embed (mask) ----
    cast_kernel<<<(DD * 256 / 4 + 255) / 256, 256, 0, stream>>>(pe_mw, wob, DD * 256);
    patchify_kernel<<<(MTOK * 256 + 255) / 256, 256, 0, stream>>>(mask, 1, pa, MTOK * 256);
    gemm_bf16<0><<<dim3(DD / 128, (MTOK + 255) / 256), 512, 0, stream>>>(
        pa, wob, pe_mb, nullptr, ttmp, MTOK, DD, 256, 0, 256, DD);
    ln_kernel<2><<<MTOK / 4, 256, 0, stream>>>(ttmp, pe_mg, pe_mbb, tokm, tokmb, MTOK, DD);

    // ---- attention bias ----
    gemm_bf16<3><<<dim3(2, 1, BB), 512, 0, stream>>>(
        tokmb, tokmb, nullptr, nullptr, biasb, NTOK, NTOK, DD, (long long)NTOK * DD, DD, DD);
    bias_edge_kernel<<<BB, 256, 0, stream>>>(biasb);

    // ---- combine + layer-0 ln1 ----
    combine_kernel<<<(MROWS * DD + 255) / 256, 256, 0, stream>>>(toki, tokm, cls, pos, x);
    ln_kernel<1><<<MROWS / 4, 256, 0, stream>>>(x, ln1_g, ln1_b, nullptr, hbuf, MROWS, DD);

    const int mblk = (MROWS + 255) / 256;   // 25
    const int wqn = 3 * DD * DD, won = DD * DD, w1n = 4 * DD * DD, w2n = 4 * DD * DD;
    const int castTot = (wqn + won + w1n + w2n) / 4;
    for (int l = 0; l < 12; ++l) {
        cast4_kernel<<<(castTot + 255) / 256, 256, 0, stream>>>(
            w_qkv + (size_t)l * wqn, wqn, w_out + (size_t)l * won, won,
            w_fc1 + (size_t)l * w1n, w1n, w_fc2 + (size_t)l * w2n, w2n,
            wqb, wob, w1b, w2b);
        gemm_bf16<4><<<dim3(3 * DD / 128, mblk), 512, 0, stream>>>(
            hbuf, wqb, b_qkv + l * 3 * DD, nullptr, qkvb, MROWS, 3 * DD, DD, 0, DD, 3 * DD);
        attn_mfma_kernel<<<dim3(HH, BB), 512, 0, stream>>>(qkvb, biasb, hbuf);
        if (l < 11) {
            // proj split-K=2 + fused res-add+ln2
            gemm_bf16<5><<<dim3(DD / 128, mblk, 2), 512, 0, stream>>>(
                hbuf, wob, nullptr, nullptr, partf, MROWS, DD, DD, 0, DD, DD);
            reduce_ln_kernel<<<MROWS / 4, 256, 0, stream>>>(
                x, partf, b_out + l * DD, ln2_g + l * DD, ln2_b + l * DD, hbuf, MROWS);
            gemm_bf16<1><<<dim3(4 * DD / 128, mblk), 512, 0, stream>>>(
                hbuf, w1b, b_fc1 + l * 4 * DD, nullptr, fc1b, MROWS, 4 * DD, DD, 0, DD, 4 * DD);
            gemm_bf16<5><<<dim3(DD / 128, mblk, 2), 512, 0, stream>>>(
                fc1b, w2b, nullptr, nullptr, partf, MROWS, DD, 4 * DD, 0, 4 * DD, DD);
            reduce_ln_kernel<<<MROWS / 4, 256, 0, stream>>>(
                x, partf, b_fc2 + l * DD, ln1_g + (l + 1) * DD, ln1_b + (l + 1) * DD,
                hbuf, MROWS);
        } else {
            // ---- layer-11 CLS-only tail: only row b*LL of x is consumed
            // downstream (final_kernel); LN/MLP are row-wise, so proj/ln2/
            // fc1/fc2 run with M=32 on the CLS rows (stride LL*DD). ----
            gemm_bf16<2><<<dim3(DD / 128, 1), 512, 0, stream>>>(
                hbuf, wob, b_out + l * DD, x, x, BB, DD, DD, 0, LLDD, LLDD);
            ln_kernel<1><<<BB / 4, 256, 0, stream>>>(
                x, ln2_g + l * DD, ln2_b + l * DD, nullptr, hbuf, BB, LLDD);
            gemm_bf16<1><<<dim3(4 * DD / 128, 1), 512, 0, stream>>>(
                hbuf, w1b, b_fc1 + l * 4 * DD, nullptr, fc1b, BB, 4 * DD, DD, 0, DD, 4 * DD);
            gemm_bf16<2><<<dim3(DD / 128, 1), 512, 0, stream>>>(
                fc1b, w2b, b_fc2 + l * DD, x, x, BB, DD, 4 * DD, 0, 4 * DD, LLDD);
        }
    }
    final_kernel<<<BB, 256, 0, stream>>>(x, enc_g, enc_b, fin_g, fin_b, head_w, head_b, (float*)d_out);
}

// Round 18
// 3127.951 us; speedup vs baseline: 1.0373x; 1.0130x over previous
//
#include <hip/hip_runtime.h>
#include <hip/hip_bf16.h>
#include <math.h>

typedef unsigned int   u32;
typedef unsigned short u16;
typedef __bf16 bf16x8 __attribute__((ext_vector_type(8)));
typedef float  f32x4  __attribute__((ext_vector_type(4)));
typedef u16    u16x8  __attribute__((ext_vector_type(8)));
typedef u16    u16x4  __attribute__((ext_vector_type(4)));

constexpr int BB = 32, DD = 768, LL = 197, HH = 12, NTOK = 196;
constexpr int MROWS = BB * LL;        // 6304
constexpr int MTOK  = BB * NTOK;      // 6272
constexpr long long LLDD = (long long)LL * DD;

__device__ __forceinline__ u16 f2bf(float f) {
    union { float f; u32 u; } v; v.f = f;
    u32 r = v.u + 0x7fff + ((v.u >> 16) & 1);
    return (u16)(r >> 16);
}
__device__ __forceinline__ float bf2f(u16 u) {
    union { u32 u; float f; } v; v.u = ((u32)u) << 16;
    return v.f;
}

#define AS1 __attribute__((address_space(1)))
#define AS3 __attribute__((address_space(3)))
__device__ __forceinline__ void gload_lds16(const void* g, void* l) {
    __builtin_amdgcn_global_load_lds((const AS1 u32*)g, (AS3 u32*)l, 16, 0, 0);
}

// ---------------------------------------------------------------------------
__global__ void cast_kernel(const float* __restrict__ in, u16* __restrict__ out, int n)
{
    int i4 = (blockIdx.x * 256 + threadIdx.x) * 4;
    if (i4 >= n) return;
    float4 v = *reinterpret_cast<const float4*>(in + i4);
    out[i4]   = f2bf(v.x); out[i4+1] = f2bf(v.y);
    out[i4+2] = f2bf(v.z); out[i4+3] = f2bf(v.w);
}

__global__ void cast4_kernel(const float* s0, int n0, const float* s1, int n1,
                             const float* s2, int n2, const float* s3, int n3,
                             u16* d0, u16* d1, u16* d2, u16* d3)
{
    int i4 = (blockIdx.x * 256 + threadIdx.x) * 4;
    const float* s; u16* d; int off;
    if      (i4 < n0)            { s = s0; d = d0; off = i4; }
    else if (i4 < n0+n1)         { s = s1; d = d1; off = i4 - n0; }
    else if (i4 < n0+n1+n2)      { s = s2; d = d2; off = i4 - n0 - n1; }
    else if (i4 < n0+n1+n2+n3)   { s = s3; d = d3; off = i4 - n0 - n1 - n2; }
    else return;
    float4 v = *reinterpret_cast<const float4*>(s + off);
    d[off]   = f2bf(v.x); d[off+1] = f2bf(v.y);
    d[off+2] = f2bf(v.z); d[off+3] = f2bf(v.w);
}

// ---------------------------------------------------------------------------
__global__ void patchify_kernel(const float* __restrict__ src, int C,
                                u16* __restrict__ out, int total)
{
    int idx = blockIdx.x * 256 + threadIdx.x;
    if (idx >= total) return;
    int K = C * 256;
    int row = idx / K, k = idx % K;
    int b = row / NTOK, n = row % NTOK;
    int c = k >> 8, rem = k & 255, pi = rem >> 4, pj = rem & 15;
    int i14 = n / 14, j14 = n % 14;
    float v = src[(((size_t)b * C + c) * 224 + i14 * 16 + pi) * 224 + j14 * 16 + pj];
    out[idx] = f2bf(v);
}

// ---------------------------------------------------------------------------
// bf16 MFMA GEMM — 256x128 tile, 8 waves, BK=32, XOR-swizzled conflict-free
// staging (r15/r16-verified) + COUNTED-VMCNT 2-DEEP pipeline (T4):
//   prologue: STAGE(0,t0); STAGE(1,t1); vmcnt(3) [t0 landed]; barrier
//   loop t:   COMPUTE(t&1)
//             barrier            [all waves done reading buf t&1]
//             STAGE(t&1, t+2); vmcnt(3)  [waits ONLY t+1's 3 loads;
//                                         t+2's 3 stay in flight]
//             barrier            [all waves' t+1 data visible]
// Every barrier is asm s_barrier WITH "memory" clobber (compiler memory
// fence — the suspected r6 fault was the fence-less builtin) and is fenced
// by sched_barrier(0) on both sides. Waitcnts are asm with memory clobber.
// Each wave's STAGE = exactly 3 global_load_lds -> vmcnt(3) counts are exact.
// MODE 0: f32 +bias   MODE 1: GELU->bf16 +bias   MODE 2: f32 +bias+res
// MODE 3: batched bias-GEMM   MODE 4: bf16 +bias
// MODE 5: split-K=2, raw f32 partial store to Cout + z*M*rsC (no bias)
// ---------------------------------------------------------------------------
#define SBAR()  do { __builtin_amdgcn_sched_barrier(0);                    \
                     asm volatile("s_barrier" ::: "memory");               \
                     __builtin_amdgcn_sched_barrier(0); } while (0)
#define WAITV3() do { asm volatile("s_waitcnt vmcnt(3)" ::: "memory");     \
                      __builtin_amdgcn_sched_barrier(0); } while (0)
#define WAITV0() do { asm volatile("s_waitcnt vmcnt(0)" ::: "memory");     \
                      __builtin_amdgcn_sched_barrier(0); } while (0)

template<int MODE>
__global__ __launch_bounds__(512) void gemm_bf16(
    const u16* __restrict__ A, const u16* __restrict__ W,
    const float* __restrict__ bias, const float* __restrict__ res,
    void* __restrict__ Cout, int M, int N, int K, long long strideA,
    long long rsA, long long rsC)
{
    __shared__ u16 As[2][8192];   // 256 rows x 32 k
    __shared__ u16 Bs[2][4096];   // 128 rows x 32 k
    const int tid  = threadIdx.x;
    const int wave = tid >> 6, lane = tid & 63;
    const int lo = lane & 15, hi = lane >> 4;
    const int wr = wave >> 1, wc = wave & 1;

    const int m0 = blockIdx.y * 256, n0 = blockIdx.x * 128;
    if (MODE == 3) { A += blockIdx.z * strideA; W += blockIdx.z * strideA; }

    const int Klen = (MODE == 5) ? (K >> 1) : K;
    const int kb   = (MODE == 5) ? blockIdx.z * Klen : 0;

    const int limA = M - 1;
    const int limB = (MODE == 3 ? M : N) - 1;
    const int srow = lane >> 2;
    const int scol = ((lane & 3) ^ ((lane >> 3) & 3)) << 3;
    int ra0 = m0 + wave * 16 + srow;        if (ra0 > limA) ra0 = limA;
    int ra1 = m0 + 128 + wave * 16 + srow;  if (ra1 > limA) ra1 = limA;
    int rb0 = n0 + wave * 16 + srow;        if (rb0 > limB) rb0 = limB;
    const u16* Arow0 = A + (size_t)ra0 * rsA + kb + scol;
    const u16* Arow1 = A + (size_t)ra1 * rsA + kb + scol;
    const u16* Brow0 = W + (size_t)rb0 * K + kb + scol;

    const int fro = lo * 32 + ((hi ^ ((lo >> 1) & 3)) << 3);

    f32x4 acc[4][4] = {};

    #define STAGE(bf_, k0_)                                         \
        do {                                                        \
            gload_lds16(Arow0 + (k0_), &As[bf_][wave * 512]);       \
            gload_lds16(Arow1 + (k0_), &As[bf_][4096 + wave * 512]);\
            gload_lds16(Brow0 + (k0_), &Bs[bf_][wave * 512]);       \
        } while (0)

    #define COMPUTE(bf_)                                                         \
        do {                                                                     \
            bf16x8 af[4], bfr[4];                                                \
            _Pragma("unroll")                                                    \
            for (int i = 0; i < 4; ++i)                                          \
                af[i] = *reinterpret_cast<const bf16x8*>(                        \
                    &As[bf_][(wr * 4 + i) * 512 + fro]);                         \
            _Pragma("unroll")                                                    \
            for (int j = 0; j < 4; ++j)                                          \
                bfr[j] = *reinterpret_cast<const bf16x8*>(                       \
                    &Bs[bf_][(wc * 4 + j) * 512 + fro]);                         \
            _Pragma("unroll")                                                    \
            for (int i = 0; i < 4; ++i)                                          \
                _Pragma("unroll")                                                \
                for (int j = 0; j < 4; ++j)                                      \
                    acc[i][j] = __builtin_amdgcn_mfma_f32_16x16x32_bf16(         \
                        af[i], bfr[j], acc[i][j], 0, 0, 0);                      \
        } while (0)

    const int nt = Klen >> 5;   // >= 8 at all call sites
    STAGE(0, 0);
    STAGE(1, 32);
    WAITV3();                    // tile0's 3 loads landed (tile1 in flight)
    SBAR();
    for (int t = 0; t < nt; ++t) {
        COMPUTE(t & 1);
        SBAR();                  // all waves done reading buf t&1
        if (t + 2 < nt) {
            STAGE(t & 1, (t + 2) * 32);
            WAITV3();            // tile t+1's 3 landed; t+2's stay in flight
        } else {
            WAITV0();
        }
        SBAR();                  // tile t+1 visible to all waves
    }
    #undef STAGE
    #undef COMPUTE

    const size_t zoff = (MODE == 5) ? (size_t)blockIdx.z * M * rsC : 0;
    const int cr = hi * 4;
    const int cc = lo;
    #pragma unroll
    for (int i = 0; i < 4; ++i) {
        #pragma unroll
        for (int r = 0; r < 4; ++r) {
            int m = m0 + wr * 64 + i * 16 + cr + r;
            if (MODE != 3 && m >= M) continue;
            #pragma unroll
            for (int j = 0; j < 4; ++j) {
                int n = n0 + wc * 64 + j * 16 + cc;
                float v = acc[i][j][r];
                if (MODE == 0) {
                    ((float*)Cout)[(size_t)m * rsC + n] = v + bias[n];
                } else if (MODE == 1) {
                    float t2 = v + bias[n];
                    t2 = 0.5f * t2 * (1.f + erff(t2 * 0.70710678118654752f));
                    ((u16*)Cout)[(size_t)m * rsC + n] = f2bf(t2);
                } else if (MODE == 2) {
                    ((float*)Cout)[(size_t)m * rsC + n] = v + bias[n] + res[(size_t)m * rsC + n];
                } else if (MODE == 4) {
                    ((u16*)Cout)[(size_t)m * rsC + n] = f2bf(v + bias[n]);
                } else if (MODE == 5) {
                    ((float*)Cout)[zoff + (size_t)m * rsC + n] = v;
                } else { // MODE 3
                    if (m < M && n < M) {
                        float* C3 = (float*)Cout + (size_t)blockIdx.z * LL * LL;
                        C3[(size_t)(m + 1) * LL + (n + 1)] = v * 0.03608439182435161f;
                    }
                }
            }
        }
    }
}

// x[i] += p0[i] + p1[i] + bias[i % N]   (split-K reduce, N % 4 == 0)
__global__ void splitk_reduce_kernel(float* __restrict__ x, const float* __restrict__ p,
                                     const float* __restrict__ bias, int MN, int N)
{
    int i4 = (blockIdx.x * 256 + threadIdx.x) * 4;
    if (i4 >= MN) return;
    float4 a  = *reinterpret_cast<const float4*>(x + i4);
    float4 p0 = *reinterpret_cast<const float4*>(p + i4);
    float4 p1 = *reinterpret_cast<const float4*>(p + (size_t)MN + i4);
    float4 b  = *reinterpret_cast<const float4*>(bias + (i4 % N));
    a.x += p0.x + p1.x + b.x;
    a.y += p0.y + p1.y + b.y;
    a.z += p0.z + p1.z + b.z;
    a.w += p0.w + p1.w + b.w;
    *reinterpret_cast<float4*>(x + i4) = a;
}

// Fused: x_row += p0+p1+bias, then LayerNorm(x_row) -> bf16 out.
__global__ __launch_bounds__(256) void reduce_ln_kernel(
    float* __restrict__ x, const float* __restrict__ p,
    const float* __restrict__ bias,
    const float* __restrict__ g, const float* __restrict__ beta,
    u16* __restrict__ outb, int nrows)
{
    int row = blockIdx.x * 4 + (threadIdx.x >> 6);
    if (row >= nrows) return;
    int lane = threadIdx.x & 63;
    size_t MN = (size_t)nrows * DD;
    float4 v[3];
    #pragma unroll
    for (int pp = 0; pp < 3; ++pp) {
        int d0 = pp * 256 + lane * 4;
        size_t ix = (size_t)row * DD + d0;
        float4 xv = *reinterpret_cast<const float4*>(x + ix);
        float4 p0 = *reinterpret_cast<const float4*>(p + ix);
        float4 p1 = *reinterpret_cast<const float4*>(p + MN + ix);
        float4 bv = *reinterpret_cast<const float4*>(bias + d0);
        xv.x += p0.x + p1.x + bv.x;
        xv.y += p0.y + p1.y + bv.y;
        xv.z += p0.z + p1.z + bv.z;
        xv.w += p0.w + p1.w + bv.w;
        *reinterpret_cast<float4*>(x + ix) = xv;
        v[pp] = xv;
    }
    float s = 0.f;
    #pragma unroll
    for (int pp = 0; pp < 3; ++pp) s += v[pp].x + v[pp].y + v[pp].z + v[pp].w;
    #pragma unroll
    for (int off = 32; off; off >>= 1) s += __shfl_xor(s, off);
    float mean = s * (1.f / 768.f);
    float q = 0.f;
    #pragma unroll
    for (int pp = 0; pp < 3; ++pp) {
        float a = v[pp].x - mean, b = v[pp].y - mean, c = v[pp].z - mean, d = v[pp].w - mean;
        q += a * a + b * b + c * c + d * d;
    }
    #pragma unroll
    for (int off = 32; off; off >>= 1) q += __shfl_xor(q, off);
    float rstd = rsqrtf(q * (1.f / 768.f) + 1e-5f);
    #pragma unroll
    for (int pp = 0; pp < 3; ++pp) {
        int d0 = pp * 256 + lane * 4;
        float4 gg = *reinterpret_cast<const float4*>(g + d0);
        float4 bb = *reinterpret_cast<const float4*>(beta + d0);
        u16x4 ob = { f2bf(gg.x * (v[pp].x - mean) * rstd + bb.x),
                     f2bf(gg.y * (v[pp].y - mean) * rstd + bb.y),
                     f2bf(gg.z * (v[pp].z - mean) * rstd + bb.z),
                     f2bf(gg.w * (v[pp].w - mean) * rstd + bb.w) };
        *reinterpret_cast<u16x4*>(outb + (size_t)row * DD + d0) = ob;
    }
}

__global__ void bias_edge_kernel(float* __restrict__ bias)
{
    int b = blockIdx.x, t = threadIdx.x;
    if (t < LL) {
        bias[((size_t)b * LL + 0) * LL + t] = 0.f;
        bias[((size_t)b * LL + t) * LL + 0] = 0.f;
    }
}

// ---------------------------------------------------------------------------
__global__ void combine_kernel(
    const float* __restrict__ toki, const float* __restrict__ tokm,
    const float* __restrict__ cls, const float* __restrict__ pos,
    float* __restrict__ x)
{
    size_t idx = (size_t)blockIdx.x * 256 + threadIdx.x;
    if (idx >= (size_t)MROWS * DD) return;
    int d = (int)(idx % DD);
    size_t bl = idx / DD;
    int l = (int)(bl % LL);
    int b = (int)(bl / LL);
    float v;
    if (l == 0) v = cls[d];
    else {
        size_t tix = ((size_t)b * NTOK + (l - 1)) * DD + d;
        v = toki[tix] + 0.5f * tokm[tix];
    }
    x[idx] = v + pos[(size_t)l * DD + d];
}

// ---------------------------------------------------------------------------
// LayerNorm: one wave per row, shfl-only, 4 rows/block; inStride for the
// layer-11 CLS gather.
// ---------------------------------------------------------------------------
template<int OUT>
__global__ __launch_bounds__(256) void ln_kernel(
    const float* __restrict__ in, const float* __restrict__ g,
    const float* __restrict__ beta, float* __restrict__ outf,
    u16* __restrict__ outb, int nrows, long long inStride)
{
    int row = blockIdx.x * 4 + (threadIdx.x >> 6);
    if (row >= nrows) return;
    int lane = threadIdx.x & 63;
    const float* xr = in + (size_t)row * inStride;
    float4 v[3];
    #pragma unroll
    for (int p = 0; p < 3; ++p)
        v[p] = *reinterpret_cast<const float4*>(xr + p * 256 + lane * 4);
    float s = 0.f;
    #pragma unroll
    for (int p = 0; p < 3; ++p) s += v[p].x + v[p].y + v[p].z + v[p].w;
    #pragma unroll
    for (int off = 32; off; off >>= 1) s += __shfl_xor(s, off);
    float mean = s * (1.f / 768.f);
    float q = 0.f;
    #pragma unroll
    for (int p = 0; p < 3; ++p) {
        float a = v[p].x - mean, b = v[p].y - mean, c = v[p].z - mean, d = v[p].w - mean;
        q += a * a + b * b + c * c + d * d;
    }
    #pragma unroll
    for (int off = 32; off; off >>= 1) q += __shfl_xor(q, off);
    float rstd = rsqrtf(q * (1.f / 768.f) + 1e-5f);
    #pragma unroll
    for (int p = 0; p < 3; ++p) {
        int d0 = p * 256 + lane * 4;
        float4 gg = *reinterpret_cast<const float4*>(g + d0);
        float4 bb = *reinterpret_cast<const float4*>(beta + d0);
        float o0 = gg.x * (v[p].x - mean) * rstd + bb.x;
        float o1 = gg.y * (v[p].y - mean) * rstd + bb.y;
        float o2 = gg.z * (v[p].z - mean) * rstd + bb.z;
        float o3 = gg.w * (v[p].w - mean) * rstd + bb.w;
        if (OUT == 0 || OUT == 2) {
            float4 of = make_float4(o0, o1, o2, o3);
            *reinterpret_cast<float4*>(outf + (size_t)row * DD + d0) = of;
        }
        if (OUT == 1 || OUT == 2) {
            u16x4 ob = { f2bf(o0), f2bf(o1), f2bf(o2), f2bf(o3) };
            *reinterpret_cast<u16x4*>(outb + (size_t)row * DD + d0) = ob;
        }
    }
}

// ---------------------------------------------------------------------------
// MFMA attention — 8 waves (r12-verified)
// ---------------------------------------------------------------------------
constexpr int KSTRE = 72;
constexpr int VSTRE = 232;
constexpr int PSTRE = 232;

__global__ __launch_bounds__(512) void attn_mfma_kernel(
    const u16* __restrict__ qkv, const float* __restrict__ bias,
    u16* __restrict__ o)
{
    const int h = blockIdx.x, b = blockIdx.y;
    const int tid = threadIdx.x, wave = tid >> 6, lane = tid & 63;
    const int lo = lane & 15, hi = lane >> 4;

    __shared__ u16 Ks[208 * KSTRE];
    __shared__ u16 Vt[64 * VSTRE];
    __shared__ u16 Ps[8][16 * PSTRE];

    const u16* qb = qkv + (size_t)b * LL * 2304;

    for (int idx = tid; idx < 208 * 8; idx += 512) {
        int key = idx >> 3, c8 = idx & 7;
        u16x8 v = {};
        if (key < LL) v = *reinterpret_cast<const u16x8*>(qb + (size_t)key * 2304 + 768 + h * 64 + c8 * 8);
        *reinterpret_cast<u16x8*>(&Ks[key * KSTRE + c8 * 8]) = v;
    }
    for (int idx = tid; idx < 224 * 8; idx += 512) {
        int key = idx >> 3, c8 = idx & 7;
        u16x8 v = {};
        if (key < LL) v = *reinterpret_cast<const u16x8*>(qb + (size_t)key * 2304 + 1536 + h * 64 + c8 * 8);
        #pragma unroll
        for (int e = 0; e < 8; ++e) Vt[(c8 * 8 + e) * VSTRE + key] = v[e];
    }
    __syncthreads();

    u16* P = Ps[wave];
    const float* biasbb = bias + (size_t)b * LL * LL;

    for (int rt = wave; rt < 13; rt += 8) {
        int q = rt * 16 + lo; if (q > LL - 1) q = LL - 1;
        const u16* qrow = qb + (size_t)q * 2304 + h * 64;
        bf16x8 qa0 = *reinterpret_cast<const bf16x8*>(qrow + hi * 8);
        bf16x8 qa1 = *reinterpret_cast<const bf16x8*>(qrow + 32 + hi * 8);

        f32x4 st[13];
        #pragma unroll
        for (int t = 0; t < 13; ++t) {
            int keyc = t * 16 + lo;
            bf16x8 kb0 = *reinterpret_cast<const bf16x8*>(&Ks[keyc * KSTRE + hi * 8]);
            bf16x8 kb1 = *reinterpret_cast<const bf16x8*>(&Ks[keyc * KSTRE + 32 + hi * 8]);
            f32x4 a = {};
            a = __builtin_amdgcn_mfma_f32_16x16x32_bf16(qa0, kb0, a, 0, 0, 0);
            a = __builtin_amdgcn_mfma_f32_16x16x32_bf16(qa1, kb1, a, 0, 0, 0);
            st[t] = a;
        }

        #pragma unroll
        for (int r = 0; r < 4; ++r) {
            int qq = rt * 16 + hi * 4 + r;
            int qc = qq > LL - 1 ? LL - 1 : qq;
            const float* brow = biasbb + (size_t)qc * LL;
            float s[13];
            float m = -1e30f;
            #pragma unroll
            for (int t = 0; t < 13; ++t) {
                int col = t * 16 + lo;
                float v;
                if (col < LL) v = st[t][r] * 0.125f + brow[col];
                else          v = -1e30f;
                s[t] = v;
                m = fmaxf(m, v);
            }
            m = fmaxf(m, __shfl_xor(m, 1));
            m = fmaxf(m, __shfl_xor(m, 2));
            m = fmaxf(m, __shfl_xor(m, 4));
            m = fmaxf(m, __shfl_xor(m, 8));
            float sum = 0.f;
            #pragma unroll
            for (int t = 0; t < 13; ++t) { float e = __expf(s[t] - m); s[t] = e; sum += e; }
            sum += __shfl_xor(sum, 1);
            sum += __shfl_xor(sum, 2);
            sum += __shfl_xor(sum, 4);
            sum += __shfl_xor(sum, 8);
            float inv = 1.f / sum;
            int prow = (hi * 4 + r) * PSTRE;
            #pragma unroll
            for (int t = 0; t < 13; ++t) P[prow + t * 16 + lo] = f2bf(s[t] * inv);
            P[prow + 208 + lo] = 0;
        }

        f32x4 oacc[4] = {};
        #pragma unroll
        for (int kt = 0; kt < 7; ++kt) {
            bf16x8 pa = *reinterpret_cast<const bf16x8*>(&P[lo * PSTRE + kt * 32 + hi * 8]);
            #pragma unroll
            for (int dt = 0; dt < 4; ++dt) {
                bf16x8 vb = *reinterpret_cast<const bf16x8*>(&Vt[(dt * 16 + lo) * VSTRE + kt * 32 + hi * 8]);
                oacc[dt] = __builtin_amdgcn_mfma_f32_16x16x32_bf16(pa, vb, oacc[dt], 0, 0, 0);
            }
        }

        #pragma unroll
        for (int dt = 0; dt < 4; ++dt) {
            #pragma unroll
            for (int r = 0; r < 4; ++r) {
                int qq = rt * 16 + hi * 4 + r;
                if (qq < LL)
                    o[((size_t)(b * LL + qq)) * DD + h * 64 + dt * 16 + lo] = f2bf(oacc[dt][r]);
            }
        }
    }
}

// ---------------------------------------------------------------------------
__global__ __launch_bounds__(256) void final_kernel(
    const float* __restrict__ x,
    const float* __restrict__ eg, const float* __restrict__ eb,
    const float* __restrict__ fg, const float* __restrict__ fb,
    const float* __restrict__ hw, const float* __restrict__ hb,
    float* __restrict__ out)
{
    int b = blockIdx.x;
    int tid = threadIdx.x;
    __shared__ float xs[768];
    __shared__ float red[256];
    const float* xr = x + (size_t)b * LL * DD;
    #pragma unroll
    for (int r = 0; r < 3; ++r) xs[tid + r * 256] = xr[tid + r * 256];
    __syncthreads();
    for (int pass = 0; pass < 2; ++pass) {
        const float* g  = pass ? fg : eg;
        const float* bb = pass ? fb : eb;
        red[tid] = xs[tid] + xs[tid + 256] + xs[tid + 512];
        __syncthreads();
        for (int off = 128; off; off >>= 1) {
            if (tid < off) red[tid] += red[tid + off];
            __syncthreads();
        }
        float mean = red[0] * (1.f / 768.f);
        __syncthreads();
        float q = 0.f;
        #pragma unroll
        for (int r = 0; r < 3; ++r) { float dv = xs[tid + r * 256] - mean; q += dv * dv; }
        red[tid] = q;
        __syncthreads();
        for (int off = 128; off; off >>= 1) {
            if (tid < off) red[tid] += red[tid + off];
            __syncthreads();
        }
        float rstd = rsqrtf(red[0] * (1.f / 768.f) + 1e-5f);
        __syncthreads();
        #pragma unroll
        for (int r = 0; r < 3; ++r) {
            int d = tid + r * 256;
            xs[d] = g[d] * (xs[d] - mean) * rstd + bb[d];
        }
        __syncthreads();
    }
    int c = tid >> 6, lane = tid & 63;
    float part = 0.f;
    for (int d = lane; d < 768; d += 64) part += xs[d] * hw[c * 768 + d];
    #pragma unroll
    for (int off = 32; off; off >>= 1) part += __shfl_down(part, off);
    if (lane == 0) out[b * 4 + c] = part + hb[c];
}

// ---------------------------------------------------------------------------
extern "C" void kernel_launch(void* const* d_in, const int* in_sizes, int n_in,
                              void* d_out, int out_size, void* d_ws, size_t ws_size,
                              hipStream_t stream)
{
    const float* img    = (const float*)d_in[0];
    const float* mask   = (const float*)d_in[1];
    const float* pe_iw  = (const float*)d_in[2];
    const float* pe_ib  = (const float*)d_in[3];
    const float* pe_ig  = (const float*)d_in[4];
    const float* pe_ibb = (const float*)d_in[5];
    const float* pe_mw  = (const float*)d_in[6];
    const float* pe_mb  = (const float*)d_in[7];
    const float* pe_mg  = (const float*)d_in[8];
    const float* pe_mbb = (const float*)d_in[9];
    const float* cls    = (const float*)d_in[10];
    const float* pos    = (const float*)d_in[11];
    const float* ln1_g  = (const float*)d_in[12];
    const float* ln1_b  = (const float*)d_in[13];
    const float* w_qkv  = (const float*)d_in[14];
    const float* b_qkv  = (const float*)d_in[15];
    const float* w_out  = (const float*)d_in[16];
    const float* b_out  = (const float*)d_in[17];
    const float* ln2_g  = (const float*)d_in[18];
    const float* ln2_b  = (const float*)d_in[19];
    const float* w_fc1  = (const float*)d_in[20];
    const float* b_fc1  = (const float*)d_in[21];
    const float* w_fc2  = (const float*)d_in[22];
    const float* b_fc2  = (const float*)d_in[23];
    const float* enc_g  = (const float*)d_in[24];
    const float* enc_b  = (const float*)d_in[25];
    const float* fin_g  = (const float*)d_in[26];
    const float* fin_b  = (const float*)d_in[27];
    const float* head_w = (const float*)d_in[28];
    const float* head_b = (const float*)d_in[29];

    char* wsb = (char*)d_ws;
    size_t off = 0;
    auto alloc = [&](size_t bytes) { void* p = wsb + off; off += (bytes + 255) & ~(size_t)255; return p; };

    float* x     = (float*)alloc((size_t)MROWS * DD * 4);
    u16*   qkvb  = (u16*)  alloc((size_t)MROWS * 3 * DD * 2);
    u16*   hbuf  = (u16*)  alloc((size_t)MROWS * DD * 2);
    u16*   fc1b  = (u16*)  alloc((size_t)MROWS * 4 * DD * 2);
    float* biasb = (float*)alloc((size_t)BB * LL * LL * 4);
    u16*   wqb   = (u16*)  alloc((size_t)3 * DD * DD * 2);
    u16*   wob   = (u16*)  alloc((size_t)DD * DD * 2);
    u16*   w1b   = (u16*)  alloc((size_t)4 * DD * DD * 2);
    u16*   w2b   = (u16*)  alloc((size_t)4 * DD * DD * 2);
    float* scratch2 = (float*)alloc((size_t)2 * MROWS * DD * 4);
    float* toki  = scratch2;
    float* tokm  = scratch2 + (size_t)MTOK * DD;
    float* partf = scratch2;
    u16*   pa    = fc1b;
    float* ttmp  = (float*)qkvb;
    u16*   tokmb = hbuf;

    // ---- patch embed (img) ----
    cast_kernel<<<(DD * DD / 4 + 255) / 256, 256, 0, stream>>>(pe_iw, wob, DD * DD);
    patchify_kernel<<<(MTOK * DD + 255) / 256, 256, 0, stream>>>(img, 3, pa, MTOK * DD);
    gemm_bf16<0><<<dim3(DD / 128, (MTOK + 255) / 256), 512, 0, stream>>>(
        pa, wob, pe_ib, nullptr, ttmp, MTOK, DD, DD, 0, DD, DD);
    ln_kernel<0><<<MTOK / 4, 256, 0, stream>>>(ttmp, pe_ig, pe_ibb, toki, nullptr, MTOK, DD);

    // ---- patch embed (mask) ----
    cast_kernel<<<(DD * 256 / 4 + 255) / 256, 256, 0, stream>>>(pe_mw, wob, DD * 256);
    patchify_kernel<<<(MTOK * 256 + 255) / 256, 256, 0, stream>>>(mask, 1, pa, MTOK * 256);
    gemm_bf16<0><<<dim3(DD / 128, (MTOK + 255) / 256), 512, 0, stream>>>(
        pa, wob, pe_mb, nullptr, ttmp, MTOK, DD, 256, 0, 256, DD);
    ln_kernel<2><<<MTOK / 4, 256, 0, stream>>>(ttmp, pe_mg, pe_mbb, tokm, tokmb, MTOK, DD);

    // ---- attention bias ----
    gemm_bf16<3><<<dim3(2, 1, BB), 512, 0, stream>>>(
        tokmb, tokmb, nullptr, nullptr, biasb, NTOK, NTOK, DD, (long long)NTOK * DD, DD, DD);
    bias_edge_kernel<<<BB, 256, 0, stream>>>(biasb);

    // ---- combine + layer-0 ln1 ----
    combine_kernel<<<(MROWS * DD + 255) / 256, 256, 0, stream>>>(toki, tokm, cls, pos, x);
    ln_kernel<1><<<MROWS / 4, 256, 0, stream>>>(x, ln1_g, ln1_b, nullptr, hbuf, MROWS, DD);

    const int mblk = (MROWS + 255) / 256;   // 25
    const int wqn = 3 * DD * DD, won = DD * DD, w1n = 4 * DD * DD, w2n = 4 * DD * DD;
    const int castTot = (wqn + won + w1n + w2n) / 4;
    for (int l = 0; l < 12; ++l) {
        cast4_kernel<<<(castTot + 255) / 256, 256, 0, stream>>>(
            w_qkv + (size_t)l * wqn, wqn, w_out + (size_t)l * won, won,
            w_fc1 + (size_t)l * w1n, w1n, w_fc2 + (size_t)l * w2n, w2n,
            wqb, wob, w1b, w2b);
        gemm_bf16<4><<<dim3(3 * DD / 128, mblk), 512, 0, stream>>>(
            hbuf, wqb, b_qkv + l * 3 * DD, nullptr, qkvb, MROWS, 3 * DD, DD, 0, DD, 3 * DD);
        attn_mfma_kernel<<<dim3(HH, BB), 512, 0, stream>>>(qkvb, biasb, hbuf);
        if (l < 11) {
            gemm_bf16<5><<<dim3(DD / 128, mblk, 2), 512, 0, stream>>>(
                hbuf, wob, nullptr, nullptr, partf, MROWS, DD, DD, 0, DD, DD);
            reduce_ln_kernel<<<MROWS / 4, 256, 0, stream>>>(
                x, partf, b_out + l * DD, ln2_g + l * DD, ln2_b + l * DD, hbuf, MROWS);
            gemm_bf16<1><<<dim3(4 * DD / 128, mblk), 512, 0, stream>>>(
                hbuf, w1b, b_fc1 + l * 4 * DD, nullptr, fc1b, MROWS, 4 * DD, DD, 0, DD, 4 * DD);
            gemm_bf16<5><<<dim3(DD / 128, mblk, 2), 512, 0, stream>>>(
                fc1b, w2b, nullptr, nullptr, partf, MROWS, DD, 4 * DD, 0, 4 * DD, DD);
            reduce_ln_kernel<<<MROWS / 4, 256, 0, stream>>>(
                x, partf, b_fc2 + l * DD, ln1_g + (l + 1) * DD, ln1_b + (l + 1) * DD,
                hbuf, MROWS);
        } else {
            // layer-11 CLS-only tail (M=32 rows at stride LL*DD)
            gemm_bf16<2><<<dim3(DD / 128, 1), 512, 0, stream>>>(
                hbuf, wob, b_out + l * DD, x, x, BB, DD, DD, 0, LLDD, LLDD);
            ln_kernel<1><<<BB / 4, 256, 0, stream>>>(
                x, ln2_g + l * DD, ln2_b + l * DD, nullptr, hbuf, BB, LLDD);
            gemm_bf16<1><<<dim3(4 * DD / 128, 1), 512, 0, stream>>>(
                hbuf, w1b, b_fc1 + l * 4 * DD, nullptr, fc1b, BB, 4 * DD, DD, 0, DD, 4 * DD);
            gemm_bf16<2><<<dim3(DD / 128, 1), 512, 0, stream>>>(
                fc1b, w2b, b_fc2 + l * DD, x, x, BB, DD, 4 * DD, 0, 4 * DD, LLDD);
        }
    }
    final_kernel<<<BB, 256, 0, stream>>>(x, enc_g, enc_b, fin_g, fin_b, head_w, head_b, (float*)d_out);
}

// Round 19
// 2969.711 us; speedup vs baseline: 1.0926x; 1.0533x over previous
//
#include <hip/hip_runtime.h>
#include <hip/hip_bf16.h>
#include <math.h>

typedef unsigned int   u32;
typedef unsigned short u16;
typedef __bf16 bf16x8 __attribute__((ext_vector_type(8)));
typedef float  f32x4  __attribute__((ext_vector_type(4)));
typedef u16    u16x8  __attribute__((ext_vector_type(8)));
typedef u16    u16x4  __attribute__((ext_vector_type(4)));

constexpr int BB = 32, DD = 768, LL = 197, HH = 12, NTOK = 196;
constexpr int MROWS = BB * LL;        // 6304
constexpr int MTOK  = BB * NTOK;      // 6272
constexpr long long LLDD = (long long)LL * DD;

__device__ __forceinline__ u16 f2bf(float f) {
    union { float f; u32 u; } v; v.f = f;
    u32 r = v.u + 0x7fff + ((v.u >> 16) & 1);
    return (u16)(r >> 16);
}
__device__ __forceinline__ float bf2f(u16 u) {
    union { u32 u; float f; } v; v.u = ((u32)u) << 16;
    return v.f;
}
// tanh-form GELU (|err| vs exact-erf gelu <= ~3e-4, far below bf16 ulp)
__device__ __forceinline__ float gelu_f(float t) {
    float u = 0.797884560802865f * (t + 0.044715f * t * t * t);
    float e = __expf(-2.f * fabsf(u));
    float th = (1.f - e) / (1.f + e);
    th = u >= 0.f ? th : -th;
    return 0.5f * t * (1.f + th);
}

#define AS1 __attribute__((address_space(1)))
#define AS3 __attribute__((address_space(3)))
__device__ __forceinline__ void gload_lds16(const void* g, void* l) {
    __builtin_amdgcn_global_load_lds((const AS1 u32*)g, (AS3 u32*)l, 16, 0, 0);
}

// ---------------------------------------------------------------------------
__global__ void cast_kernel(const float* __restrict__ in, u16* __restrict__ out, int n)
{
    int i4 = (blockIdx.x * 256 + threadIdx.x) * 4;
    if (i4 >= n) return;
    float4 v = *reinterpret_cast<const float4*>(in + i4);
    out[i4]   = f2bf(v.x); out[i4+1] = f2bf(v.y);
    out[i4+2] = f2bf(v.z); out[i4+3] = f2bf(v.w);
}

__global__ void cast4_kernel(const float* s0, int n0, const float* s1, int n1,
                             const float* s2, int n2, const float* s3, int n3,
                             u16* d0, u16* d1, u16* d2, u16* d3)
{
    int i4 = (blockIdx.x * 256 + threadIdx.x) * 4;
    const float* s; u16* d; int off;
    if      (i4 < n0)            { s = s0; d = d0; off = i4; }
    else if (i4 < n0+n1)         { s = s1; d = d1; off = i4 - n0; }
    else if (i4 < n0+n1+n2)      { s = s2; d = d2; off = i4 - n0 - n1; }
    else if (i4 < n0+n1+n2+n3)   { s = s3; d = d3; off = i4 - n0 - n1 - n2; }
    else return;
    float4 v = *reinterpret_cast<const float4*>(s + off);
    d[off]   = f2bf(v.x); d[off+1] = f2bf(v.y);
    d[off+2] = f2bf(v.z); d[off+3] = f2bf(v.w);
}

// ---------------------------------------------------------------------------
__global__ void patchify_kernel(const float* __restrict__ src, int C,
                                u16* __restrict__ out, int total)
{
    int idx = blockIdx.x * 256 + threadIdx.x;
    if (idx >= total) return;
    int K = C * 256;
    int row = idx / K, k = idx % K;
    int b = row / NTOK, n = row % NTOK;
    int c = k >> 8, rem = k & 255, pi = rem >> 4, pj = rem & 15;
    int i14 = n / 14, j14 = n % 14;
    float v = src[(((size_t)b * C + c) * 224 + i14 * 16 + pi) * 224 + j14 * 16 + pj];
    out[idx] = f2bf(v);
}

// ---------------------------------------------------------------------------
// bf16 MFMA GEMM — 256x128 tile, 8 waves, BK=32, XOR-swizzled conflict-free
// staging + counted-vmcnt 2-deep pipeline (r18-verified correct).
// MODE 0: f32 +bias   MODE 1: GELU(tanh)->bf16 +bias   MODE 2: f32 +bias+res
// MODE 3: batched bias-GEMM   MODE 4: bf16 +bias
// MODE 5: split-K=2, bf16 partial store to Cout + z*M*rsC (no bias)
// ---------------------------------------------------------------------------
#define SBAR()  do { __builtin_amdgcn_sched_barrier(0);                    \
                     asm volatile("s_barrier" ::: "memory");               \
                     __builtin_amdgcn_sched_barrier(0); } while (0)
#define WAITV3() do { asm volatile("s_waitcnt vmcnt(3)" ::: "memory");     \
                      __builtin_amdgcn_sched_barrier(0); } while (0)
#define WAITV0() do { asm volatile("s_waitcnt vmcnt(0)" ::: "memory");     \
                      __builtin_amdgcn_sched_barrier(0); } while (0)

template<int MODE>
__global__ __launch_bounds__(512) void gemm_bf16(
    const u16* __restrict__ A, const u16* __restrict__ W,
    const float* __restrict__ bias, const float* __restrict__ res,
    void* __restrict__ Cout, int M, int N, int K, long long strideA,
    long long rsA, long long rsC)
{
    __shared__ u16 As[2][8192];   // 256 rows x 32 k
    __shared__ u16 Bs[2][4096];   // 128 rows x 32 k
    const int tid  = threadIdx.x;
    const int wave = tid >> 6, lane = tid & 63;
    const int lo = lane & 15, hi = lane >> 4;
    const int wr = wave >> 1, wc = wave & 1;

    const int m0 = blockIdx.y * 256, n0 = blockIdx.x * 128;
    if (MODE == 3) { A += blockIdx.z * strideA; W += blockIdx.z * strideA; }

    const int Klen = (MODE == 5) ? (K >> 1) : K;
    const int kb   = (MODE == 5) ? blockIdx.z * Klen : 0;

    const int limA = M - 1;
    const int limB = (MODE == 3 ? M : N) - 1;
    const int srow = lane >> 2;
    const int scol = ((lane & 3) ^ ((lane >> 3) & 3)) << 3;
    int ra0 = m0 + wave * 16 + srow;        if (ra0 > limA) ra0 = limA;
    int ra1 = m0 + 128 + wave * 16 + srow;  if (ra1 > limA) ra1 = limA;
    int rb0 = n0 + wave * 16 + srow;        if (rb0 > limB) rb0 = limB;
    const u16* Arow0 = A + (size_t)ra0 * rsA + kb + scol;
    const u16* Arow1 = A + (size_t)ra1 * rsA + kb + scol;
    const u16* Brow0 = W + (size_t)rb0 * K + kb + scol;

    const int fro = lo * 32 + ((hi ^ ((lo >> 1) & 3)) << 3);

    f32x4 acc[4][4] = {};

    #define STAGE(bf_, k0_)                                         \
        do {                                                        \
            gload_lds16(Arow0 + (k0_), &As[bf_][wave * 512]);       \
            gload_lds16(Arow1 + (k0_), &As[bf_][4096 + wave * 512]);\
            gload_lds16(Brow0 + (k0_), &Bs[bf_][wave * 512]);       \
        } while (0)

    #define COMPUTE(bf_)                                                         \
        do {                                                                     \
            bf16x8 af[4], bfr[4];                                                \
            _Pragma("unroll")                                                    \
            for (int i = 0; i < 4; ++i)                                          \
                af[i] = *reinterpret_cast<const bf16x8*>(                        \
                    &As[bf_][(wr * 4 + i) * 512 + fro]);                         \
            _Pragma("unroll")                                                    \
            for (int j = 0; j < 4; ++j)                                          \
                bfr[j] = *reinterpret_cast<const bf16x8*>(                       \
                    &Bs[bf_][(wc * 4 + j) * 512 + fro]);                         \
            _Pragma("unroll")                                                    \
            for (int i = 0; i < 4; ++i)                                          \
                _Pragma("unroll")                                                \
                for (int j = 0; j < 4; ++j)                                      \
                    acc[i][j] = __builtin_amdgcn_mfma_f32_16x16x32_bf16(         \
                        af[i], bfr[j], acc[i][j], 0, 0, 0);                      \
        } while (0)

    const int nt = Klen >> 5;
    STAGE(0, 0);
    STAGE(1, 32);
    WAITV3();
    SBAR();
    for (int t = 0; t < nt; ++t) {
        COMPUTE(t & 1);
        SBAR();
        if (t + 2 < nt) {
            STAGE(t & 1, (t + 2) * 32);
            WAITV3();
        } else {
            WAITV0();
        }
        SBAR();
    }
    #undef STAGE
    #undef COMPUTE

    const size_t zoff = (MODE == 5) ? (size_t)blockIdx.z * M * rsC : 0;
    const int cr = hi * 4;
    const int cc = lo;
    #pragma unroll
    for (int i = 0; i < 4; ++i) {
        #pragma unroll
        for (int r = 0; r < 4; ++r) {
            int m = m0 + wr * 64 + i * 16 + cr + r;
            if (MODE != 3 && m >= M) continue;
            #pragma unroll
            for (int j = 0; j < 4; ++j) {
                int n = n0 + wc * 64 + j * 16 + cc;
                float v = acc[i][j][r];
                if (MODE == 0) {
                    ((float*)Cout)[(size_t)m * rsC + n] = v + bias[n];
                } else if (MODE == 1) {
                    ((u16*)Cout)[(size_t)m * rsC + n] = f2bf(gelu_f(v + bias[n]));
                } else if (MODE == 2) {
                    ((float*)Cout)[(size_t)m * rsC + n] = v + bias[n] + res[(size_t)m * rsC + n];
                } else if (MODE == 4) {
                    ((u16*)Cout)[(size_t)m * rsC + n] = f2bf(v + bias[n]);
                } else if (MODE == 5) {
                    ((u16*)Cout)[zoff + (size_t)m * rsC + n] = f2bf(v);
                } else { // MODE 3
                    if (m < M && n < M) {
                        float* C3 = (float*)Cout + (size_t)blockIdx.z * LL * LL;
                        C3[(size_t)(m + 1) * LL + (n + 1)] = v * 0.03608439182435161f;
                    }
                }
            }
        }
    }
}

// Fused: x_row += bf16(p0)+bf16(p1)+bias, then LayerNorm(x_row) -> bf16 out.
// partf (scratch2, bf16) is disjoint from x and outb=hbuf (r14-verified).
__global__ __launch_bounds__(256) void reduce_ln_kernel(
    float* __restrict__ x, const u16* __restrict__ p,
    const float* __restrict__ bias,
    const float* __restrict__ g, const float* __restrict__ beta,
    u16* __restrict__ outb, int nrows)
{
    int row = blockIdx.x * 4 + (threadIdx.x >> 6);
    if (row >= nrows) return;
    int lane = threadIdx.x & 63;
    size_t MN = (size_t)nrows * DD;
    float4 v[3];
    #pragma unroll
    for (int pp = 0; pp < 3; ++pp) {
        int d0 = pp * 256 + lane * 4;
        size_t ix = (size_t)row * DD + d0;
        float4 xv = *reinterpret_cast<const float4*>(x + ix);
        u16x4 p0 = *reinterpret_cast<const u16x4*>(p + ix);
        u16x4 p1 = *reinterpret_cast<const u16x4*>(p + MN + ix);
        float4 bv = *reinterpret_cast<const float4*>(bias + d0);
        xv.x += bf2f(p0[0]) + bf2f(p1[0]) + bv.x;
        xv.y += bf2f(p0[1]) + bf2f(p1[1]) + bv.y;
        xv.z += bf2f(p0[2]) + bf2f(p1[2]) + bv.z;
        xv.w += bf2f(p0[3]) + bf2f(p1[3]) + bv.w;
        *reinterpret_cast<float4*>(x + ix) = xv;
        v[pp] = xv;
    }
    float s = 0.f;
    #pragma unroll
    for (int pp = 0; pp < 3; ++pp) s += v[pp].x + v[pp].y + v[pp].z + v[pp].w;
    #pragma unroll
    for (int off = 32; off; off >>= 1) s += __shfl_xor(s, off);
    float mean = s * (1.f / 768.f);
    float q = 0.f;
    #pragma unroll
    for (int pp = 0; pp < 3; ++pp) {
        float a = v[pp].x - mean, b = v[pp].y - mean, c = v[pp].z - mean, d = v[pp].w - mean;
        q += a * a + b * b + c * c + d * d;
    }
    #pragma unroll
    for (int off = 32; off; off >>= 1) q += __shfl_xor(q, off);
    float rstd = rsqrtf(q * (1.f / 768.f) + 1e-5f);
    #pragma unroll
    for (int pp = 0; pp < 3; ++pp) {
        int d0 = pp * 256 + lane * 4;
        float4 gg = *reinterpret_cast<const float4*>(g + d0);
        float4 bb = *reinterpret_cast<const float4*>(beta + d0);
        u16x4 ob = { f2bf(gg.x * (v[pp].x - mean) * rstd + bb.x),
                     f2bf(gg.y * (v[pp].y - mean) * rstd + bb.y),
                     f2bf(gg.z * (v[pp].z - mean) * rstd + bb.z),
                     f2bf(gg.w * (v[pp].w - mean) * rstd + bb.w) };
        *reinterpret_cast<u16x4*>(outb + (size_t)row * DD + d0) = ob;
    }
}

__global__ void bias_edge_kernel(float* __restrict__ bias)
{
    int b = blockIdx.x, t = threadIdx.x;
    if (t < LL) {
        bias[((size_t)b * LL + 0) * LL + t] = 0.f;
        bias[((size_t)b * LL + t) * LL + 0] = 0.f;
    }
}

// ---------------------------------------------------------------------------
__global__ void combine_kernel(
    const float* __restrict__ toki, const float* __restrict__ tokm,
    const float* __restrict__ cls, const float* __restrict__ pos,
    float* __restrict__ x)
{
    size_t idx = (size_t)blockIdx.x * 256 + threadIdx.x;
    if (idx >= (size_t)MROWS * DD) return;
    int d = (int)(idx % DD);
    size_t bl = idx / DD;
    int l = (int)(bl % LL);
    int b = (int)(bl / LL);
    float v;
    if (l == 0) v = cls[d];
    else {
        size_t tix = ((size_t)b * NTOK + (l - 1)) * DD + d;
        v = toki[tix] + 0.5f * tokm[tix];
    }
    x[idx] = v + pos[(size_t)l * DD + d];
}

// ---------------------------------------------------------------------------
// LayerNorm: one wave per row, shfl-only, 4 rows/block; inStride for the
// layer-11 CLS gather.
// ---------------------------------------------------------------------------
template<int OUT>
__global__ __launch_bounds__(256) void ln_kernel(
    const float* __restrict__ in, const float* __restrict__ g,
    const float* __restrict__ beta, float* __restrict__ outf,
    u16* __restrict__ outb, int nrows, long long inStride)
{
    int row = blockIdx.x * 4 + (threadIdx.x >> 6);
    if (row >= nrows) return;
    int lane = threadIdx.x & 63;
    const float* xr = in + (size_t)row * inStride;
    float4 v[3];
    #pragma unroll
    for (int p = 0; p < 3; ++p)
        v[p] = *reinterpret_cast<const float4*>(xr + p * 256 + lane * 4);
    float s = 0.f;
    #pragma unroll
    for (int p = 0; p < 3; ++p) s += v[p].x + v[p].y + v[p].z + v[p].w;
    #pragma unroll
    for (int off = 32; off; off >>= 1) s += __shfl_xor(s, off);
    float mean = s * (1.f / 768.f);
    float q = 0.f;
    #pragma unroll
    for (int p = 0; p < 3; ++p) {
        float a = v[p].x - mean, b = v[p].y - mean, c = v[p].z - mean, d = v[p].w - mean;
        q += a * a + b * b + c * c + d * d;
    }
    #pragma unroll
    for (int off = 32; off; off >>= 1) q += __shfl_xor(q, off);
    float rstd = rsqrtf(q * (1.f / 768.f) + 1e-5f);
    #pragma unroll
    for (int p = 0; p < 3; ++p) {
        int d0 = p * 256 + lane * 4;
        float4 gg = *reinterpret_cast<const float4*>(g + d0);
        float4 bb = *reinterpret_cast<const float4*>(beta + d0);
        float o0 = gg.x * (v[p].x - mean) * rstd + bb.x;
        float o1 = gg.y * (v[p].y - mean) * rstd + bb.y;
        float o2 = gg.z * (v[p].z - mean) * rstd + bb.z;
        float o3 = gg.w * (v[p].w - mean) * rstd + bb.w;
        if (OUT == 0 || OUT == 2) {
            float4 of = make_float4(o0, o1, o2, o3);
            *reinterpret_cast<float4*>(outf + (size_t)row * DD + d0) = of;
        }
        if (OUT == 1 || OUT == 2) {
            u16x4 ob = { f2bf(o0), f2bf(o1), f2bf(o2), f2bf(o3) };
            *reinterpret_cast<u16x4*>(outb + (size_t)row * DD + d0) = ob;
        }
    }
}

// ---------------------------------------------------------------------------
// MFMA attention — 8 waves (r12-verified)
// ---------------------------------------------------------------------------
constexpr int KSTRE = 72;
constexpr int VSTRE = 232;
constexpr int PSTRE = 232;

__global__ __launch_bounds__(512) void attn_mfma_kernel(
    const u16* __restrict__ qkv, const float* __restrict__ bias,
    u16* __restrict__ o)
{
    const int h = blockIdx.x, b = blockIdx.y;
    const int tid = threadIdx.x, wave = tid >> 6, lane = tid & 63;
    const int lo = lane & 15, hi = lane >> 4;

    __shared__ u16 Ks[208 * KSTRE];
    __shared__ u16 Vt[64 * VSTRE];
    __shared__ u16 Ps[8][16 * PSTRE];

    const u16* qb = qkv + (size_t)b * LL * 2304;

    for (int idx = tid; idx < 208 * 8; idx += 512) {
        int key = idx >> 3, c8 = idx & 7;
        u16x8 v = {};
        if (key < LL) v = *reinterpret_cast<const u16x8*>(qb + (size_t)key * 2304 + 768 + h * 64 + c8 * 8);
        *reinterpret_cast<u16x8*>(&Ks[key * KSTRE + c8 * 8]) = v;
    }
    for (int idx = tid; idx < 224 * 8; idx += 512) {
        int key = idx >> 3, c8 = idx & 7;
        u16x8 v = {};
        if (key < LL) v = *reinterpret_cast<const u16x8*>(qb + (size_t)key * 2304 + 1536 + h * 64 + c8 * 8);
        #pragma unroll
        for (int e = 0; e < 8; ++e) Vt[(c8 * 8 + e) * VSTRE + key] = v[e];
    }
    __syncthreads();

    u16* P = Ps[wave];
    const float* biasbb = bias + (size_t)b * LL * LL;

    for (int rt = wave; rt < 13; rt += 8) {
        int q = rt * 16 + lo; if (q > LL - 1) q = LL - 1;
        const u16* qrow = qb + (size_t)q * 2304 + h * 64;
        bf16x8 qa0 = *reinterpret_cast<const bf16x8*>(qrow + hi * 8);
        bf16x8 qa1 = *reinterpret_cast<const bf16x8*>(qrow + 32 + hi * 8);

        f32x4 st[13];
        #pragma unroll
        for (int t = 0; t < 13; ++t) {
            int keyc = t * 16 + lo;
            bf16x8 kb0 = *reinterpret_cast<const bf16x8*>(&Ks[keyc * KSTRE + hi * 8]);
            bf16x8 kb1 = *reinterpret_cast<const bf16x8*>(&Ks[keyc * KSTRE + 32 + hi * 8]);
            f32x4 a = {};
            a = __builtin_amdgcn_mfma_f32_16x16x32_bf16(qa0, kb0, a, 0, 0, 0);
            a = __builtin_amdgcn_mfma_f32_16x16x32_bf16(qa1, kb1, a, 0, 0, 0);
            st[t] = a;
        }

        #pragma unroll
        for (int r = 0; r < 4; ++r) {
            int qq = rt * 16 + hi * 4 + r;
            int qc = qq > LL - 1 ? LL - 1 : qq;
            const float* brow = biasbb + (size_t)qc * LL;
            float s[13];
            float m = -1e30f;
            #pragma unroll
            for (int t = 0; t < 13; ++t) {
                int col = t * 16 + lo;
                float v;
                if (col < LL) v = st[t][r] * 0.125f + brow[col];
                else          v = -1e30f;
                s[t] = v;
                m = fmaxf(m, v);
            }
            m = fmaxf(m, __shfl_xor(m, 1));
            m = fmaxf(m, __shfl_xor(m, 2));
            m = fmaxf(m, __shfl_xor(m, 4));
            m = fmaxf(m, __shfl_xor(m, 8));
            float sum = 0.f;
            #pragma unroll
            for (int t = 0; t < 13; ++t) { float e = __expf(s[t] - m); s[t] = e; sum += e; }
            sum += __shfl_xor(sum, 1);
            sum += __shfl_xor(sum, 2);
            sum += __shfl_xor(sum, 4);
            sum += __shfl_xor(sum, 8);
            float inv = 1.f / sum;
            int prow = (hi * 4 + r) * PSTRE;
            #pragma unroll
            for (int t = 0; t < 13; ++t) P[prow + t * 16 + lo] = f2bf(s[t] * inv);
            P[prow + 208 + lo] = 0;
        }

        f32x4 oacc[4] = {};
        #pragma unroll
        for (int kt = 0; kt < 7; ++kt) {
            bf16x8 pa = *reinterpret_cast<const bf16x8*>(&P[lo * PSTRE + kt * 32 + hi * 8]);
            #pragma unroll
            for (int dt = 0; dt < 4; ++dt) {
                bf16x8 vb = *reinterpret_cast<const bf16x8*>(&Vt[(dt * 16 + lo) * VSTRE + kt * 32 + hi * 8]);
                oacc[dt] = __builtin_amdgcn_mfma_f32_16x16x32_bf16(pa, vb, oacc[dt], 0, 0, 0);
            }
        }

        #pragma unroll
        for (int dt = 0; dt < 4; ++dt) {
            #pragma unroll
            for (int r = 0; r < 4; ++r) {
                int qq = rt * 16 + hi * 4 + r;
                if (qq < LL)
                    o[((size_t)(b * LL + qq)) * DD + h * 64 + dt * 16 + lo] = f2bf(oacc[dt][r]);
            }
        }
    }
}

// ---------------------------------------------------------------------------
__global__ __launch_bounds__(256) void final_kernel(
    const float* __restrict__ x,
    const float* __restrict__ eg, const float* __restrict__ eb,
    const float* __restrict__ fg, const float* __restrict__ fb,
    const float* __restrict__ hw, const float* __restrict__ hb,
    float* __restrict__ out)
{
    int b = blockIdx.x;
    int tid = threadIdx.x;
    __shared__ float xs[768];
    __shared__ float red[256];
    const float* xr = x + (size_t)b * LL * DD;
    #pragma unroll
    for (int r = 0; r < 3; ++r) xs[tid + r * 256] = xr[tid + r * 256];
    __syncthreads();
    for (int pass = 0; pass < 2; ++pass) {
        const float* g  = pass ? fg : eg;
        const float* bb = pass ? fb : eb;
        red[tid] = xs[tid] + xs[tid + 256] + xs[tid + 512];
        __syncthreads();
        for (int off = 128; off; off >>= 1) {
            if (tid < off) red[tid] += red[tid + off];
            __syncthreads();
        }
        float mean = red[0] * (1.f / 768.f);
        __syncthreads();
        float q = 0.f;
        #pragma unroll
        for (int r = 0; r < 3; ++r) { float dv = xs[tid + r * 256] - mean; q += dv * dv; }
        red[tid] = q;
        __syncthreads();
        for (int off = 128; off; off >>= 1) {
            if (tid < off) red[tid] += red[tid + off];
            __syncthreads();
        }
        float rstd = rsqrtf(red[0] * (1.f / 768.f) + 1e-5f);
        __syncthreads();
        #pragma unroll
        for (int r = 0; r < 3; ++r) {
            int d = tid + r * 256;
            xs[d] = g[d] * (xs[d] - mean) * rstd + bb[d];
        }
        __syncthreads();
    }
    int c = tid >> 6, lane = tid & 63;
    float part = 0.f;
    for (int d = lane; d < 768; d += 64) part += xs[d] * hw[c * 768 + d];
    #pragma unroll
    for (int off = 32; off; off >>= 1) part += __shfl_down(part, off);
    if (lane == 0) out[b * 4 + c] = part + hb[c];
}

// ---------------------------------------------------------------------------
extern "C" void kernel_launch(void* const* d_in, const int* in_sizes, int n_in,
                              void* d_out, int out_size, void* d_ws, size_t ws_size,
                              hipStream_t stream)
{
    const float* img    = (const float*)d_in[0];
    const float* mask   = (const float*)d_in[1];
    const float* pe_iw  = (const float*)d_in[2];
    const float* pe_ib  = (const float*)d_in[3];
    const float* pe_ig  = (const float*)d_in[4];
    const float* pe_ibb = (const float*)d_in[5];
    const float* pe_mw  = (const float*)d_in[6];
    const float* pe_mb  = (const float*)d_in[7];
    const float* pe_mg  = (const float*)d_in[8];
    const float* pe_mbb = (const float*)d_in[9];
    const float* cls    = (const float*)d_in[10];
    const float* pos    = (const float*)d_in[11];
    const float* ln1_g  = (const float*)d_in[12];
    const float* ln1_b  = (const float*)d_in[13];
    const float* w_qkv  = (const float*)d_in[14];
    const float* b_qkv  = (const float*)d_in[15];
    const float* w_out  = (const float*)d_in[16];
    const float* b_out  = (const float*)d_in[17];
    const float* ln2_g  = (const float*)d_in[18];
    const float* ln2_b  = (const float*)d_in[19];
    const float* w_fc1  = (const float*)d_in[20];
    const float* b_fc1  = (const float*)d_in[21];
    const float* w_fc2  = (const float*)d_in[22];
    const float* b_fc2  = (const float*)d_in[23];
    const float* enc_g  = (const float*)d_in[24];
    const float* enc_b  = (const float*)d_in[25];
    const float* fin_g  = (const float*)d_in[26];
    const float* fin_b  = (const float*)d_in[27];
    const float* head_w = (const float*)d_in[28];
    const float* head_b = (const float*)d_in[29];

    char* wsb = (char*)d_ws;
    size_t off = 0;
    auto alloc = [&](size_t bytes) { void* p = wsb + off; off += (bytes + 255) & ~(size_t)255; return p; };

    float* x     = (float*)alloc((size_t)MROWS * DD * 4);
    u16*   qkvb  = (u16*)  alloc((size_t)MROWS * 3 * DD * 2);
    u16*   hbuf  = (u16*)  alloc((size_t)MROWS * DD * 2);
    u16*   fc1b  = (u16*)  alloc((size_t)MROWS * 4 * DD * 2);
    float* biasb = (float*)alloc((size_t)BB * LL * LL * 4);
    u16*   wqb   = (u16*)  alloc((size_t)3 * DD * DD * 2);
    u16*   wob   = (u16*)  alloc((size_t)DD * DD * 2);
    u16*   w1b   = (u16*)  alloc((size_t)4 * DD * DD * 2);
    u16*   w2b   = (u16*)  alloc((size_t)4 * DD * DD * 2);
    float* scratch2 = (float*)alloc((size_t)2 * MROWS * DD * 4);
    float* toki  = scratch2;
    float* tokm  = scratch2 + (size_t)MTOK * DD;
    u16*   partb = (u16*)scratch2;          // bf16 split-K partials (2 x MROWS*DD)
    u16*   pa    = fc1b;
    float* ttmp  = (float*)qkvb;
    u16*   tokmb = hbuf;

    // ---- patch embed (img) ----
    cast_kernel<<<(DD * DD / 4 + 255) / 256, 256, 0, stream>>>(pe_iw, wob, DD * DD);
    patchify_kernel<<<(MTOK * DD + 255) / 256, 256, 0, stream>>>(img, 3, pa, MTOK * DD);
    gemm_bf16<0><<<dim3(DD / 128, (MTOK + 255) / 256), 512, 0, stream>>>(
        pa, wob, pe_ib, nullptr, ttmp, MTOK, DD, DD, 0, DD, DD);
    ln_kernel<0><<<MTOK / 4, 256, 0, stream>>>(ttmp, pe_ig, pe_ibb, toki, nullptr, MTOK, DD);

    // ---- patch embed (mask) ----
    cast_kernel<<<(DD * 256 / 4 + 255) / 256, 256, 0, stream>>>(pe_mw, wob, DD * 256);
    patchify_kernel<<<(MTOK * 256 + 255) / 256, 256, 0, stream>>>(mask, 1, pa, MTOK * 256);
    gemm_bf16<0><<<dim3(DD / 128, (MTOK + 255) / 256), 512, 0, stream>>>(
        pa, wob, pe_mb, nullptr, ttmp, MTOK, DD, 256, 0, 256, DD);
    ln_kernel<2><<<MTOK / 4, 256, 0, stream>>>(ttmp, pe_mg, pe_mbb, tokm, tokmb, MTOK, DD);

    // ---- attention bias ----
    gemm_bf16<3><<<dim3(2, 1, BB), 512, 0, stream>>>(
        tokmb, tokmb, nullptr, nullptr, biasb, NTOK, NTOK, DD, (long long)NTOK * DD, DD, DD);
    bias_edge_kernel<<<BB, 256, 0, stream>>>(biasb);

    // ---- combine + layer-0 ln1 ----
    combine_kernel<<<(MROWS * DD + 255) / 256, 256, 0, stream>>>(toki, tokm, cls, pos, x);
    ln_kernel<1><<<MROWS / 4, 256, 0, stream>>>(x, ln1_g, ln1_b, nullptr, hbuf, MROWS, DD);

    const int mblk = (MROWS + 255) / 256;   // 25
    const int wqn = 3 * DD * DD, won = DD * DD, w1n = 4 * DD * DD, w2n = 4 * DD * DD;
    const int castTot = (wqn + won + w1n + w2n) / 4;
    for (int l = 0; l < 12; ++l) {
        cast4_kernel<<<(castTot + 255) / 256, 256, 0, stream>>>(
            w_qkv + (size_t)l * wqn, wqn, w_out + (size_t)l * won, won,
            w_fc1 + (size_t)l * w1n, w1n, w_fc2 + (size_t)l * w2n, w2n,
            wqb, wob, w1b, w2b);
        gemm_bf16<4><<<dim3(3 * DD / 128, mblk), 512, 0, stream>>>(
            hbuf, wqb, b_qkv + l * 3 * DD, nullptr, qkvb, MROWS, 3 * DD, DD, 0, DD, 3 * DD);
        attn_mfma_kernel<<<dim3(HH, BB), 512, 0, stream>>>(qkvb, biasb, hbuf);
        if (l < 11) {
            gemm_bf16<5><<<dim3(DD / 128, mblk, 2), 512, 0, stream>>>(
                hbuf, wob, nullptr, nullptr, partb, MROWS, DD, DD, 0, DD, DD);
            reduce_ln_kernel<<<MROWS / 4, 256, 0, stream>>>(
                x, partb, b_out + l * DD, ln2_g + l * DD, ln2_b + l * DD, hbuf, MROWS);
            gemm_bf16<1><<<dim3(4 * DD / 128, mblk), 512, 0, stream>>>(
                hbuf, w1b, b_fc1 + l * 4 * DD, nullptr, fc1b, MROWS, 4 * DD, DD, 0, DD, 4 * DD);
            gemm_bf16<5><<<dim3(DD / 128, mblk, 2), 512, 0, stream>>>(
                fc1b, w2b, nullptr, nullptr, partb, MROWS, DD, 4 * DD, 0, 4 * DD, DD);
            reduce_ln_kernel<<<MROWS / 4, 256, 0, stream>>>(
                x, partb, b_fc2 + l * DD, ln1_g + (l + 1) * DD, ln1_b + (l + 1) * DD,
                hbuf, MROWS);
        } else {
            // layer-11 CLS-only tail (M=32 rows at stride LL*DD)
            gemm_bf16<2><<<dim3(DD / 128, 1), 512, 0, stream>>>(
                hbuf, wob, b_out + l * DD, x, x, BB, DD, DD, 0, LLDD, LLDD);
            ln_kernel<1><<<BB / 4, 256, 0, stream>>>(
                x, ln2_g + l * DD, ln2_b + l * DD, nullptr, hbuf, BB, LLDD);
            gemm_bf16<1><<<dim3(4 * DD / 128, 1), 512, 0, stream>>>(
                hbuf, w1b, b_fc1 + l * 4 * DD, nullptr, fc1b, BB, 4 * DD, DD, 0, DD, 4 * DD);
            gemm_bf16<2><<<dim3(DD / 128, 1), 512, 0, stream>>>(
                fc1b, w2b, b_fc2 + l * DD, x, x, BB, DD, 4 * DD, 0, 4 * DD, LLDD);
        }
    }
    final_kernel<<<BB, 256, 0, stream>>>(x, enc_g, enc_b, fin_g, fin_b, head_w, head_b, (float*)d_out);
}